// Round 2
// baseline (606.722 us; speedup 1.0000x reference)
//
#include <hip/hip_runtime.h>

typedef unsigned short u16;
typedef __attribute__((ext_vector_type(8))) short s16x8;
typedef __attribute__((ext_vector_type(4))) float f32x4;

__device__ __forceinline__ u16 f2bf(float f){
  union { float f; unsigned u; } v; v.f = f;
  unsigned r = v.u + 0x7FFFu + ((v.u >> 16) & 1u);
  return (u16)(r >> 16);
}
__device__ __forceinline__ float bf2f(u16 h){
  union { unsigned u; float f; } v; v.u = ((unsigned)h) << 16;
  return v.f;
}
__device__ __forceinline__ f32x4 mfma16(s16x8 a, s16x8 b, f32x4 c){
  return __builtin_amdgcn_mfma_f32_16x16x32_bf16(a, b, c, 0, 0, 0);
}

// ---------------------------------------------------------------------------
// K0: weight transpose + bf16 convert.  WT[k][c] = bf16(W[c][k])
// ---------------------------------------------------------------------------
__global__ __launch_bounds__(256) void k0_transform(
    const float* __restrict__ W_in, const float* __restrict__ W_inter, const float* __restrict__ W_last,
    u16* __restrict__ WT_in, u16* __restrict__ WTi, u16* __restrict__ WTl)
{
  const int t = blockIdx.x * 256 + threadIdx.x;
  if (t < 1536 * 512){ const int k = t >> 9, c = t & 511; WT_in[t] = f2bf(W_in[c * 1536 + k]); }
  if (t < 512 * 512){ const int k = t >> 9, c = t & 511; WTi[t] = f2bf(W_inter[c * 512 + k]); WTl[t] = f2bf(W_last[c * 512 + k]); }
}

// ---------------------------------------------------------------------------
// K1: qkv = x @ W_in + b_in.  x:[b][p=n*64+d][512] f32.
// Q,K -> planes [b][k][4096] bf16;  V -> [b][p][512] bf16 (pos-major).
// ---------------------------------------------------------------------------
__global__ __launch_bounds__(256) void k1_qkv(
    const float* __restrict__ x, const u16* __restrict__ WT_in, const float* __restrict__ b_in,
    u16* __restrict__ Qp, u16* __restrict__ Kp, u16* __restrict__ TV)
{
  __shared__ u16 A_lds[64][72];           // [pos][c], +8 pad -> conflict-free frag reads
  const int kt = blockIdx.x;
  const int p0 = blockIdx.y * 64;
  const int b  = blockIdx.z;
  const int tid = threadIdx.x;
  const int w = tid >> 6, l = tid & 63;
  const int l15 = l & 15, lg = l >> 4;
  const int kbase = kt * 256 + w * 64;

  f32x4 acc[4][4] = {};
  const float* xrow = x + ((size_t)b * 4096 + p0) * 512;
  const int sr = tid >> 2, sc = (tid & 3) * 16;

  for (int c0 = 0; c0 < 512; c0 += 64){
    __syncthreads();
    { // stage 64x64 f32 -> bf16 LDS
      const f32x4* src = (const f32x4*)(xrow + sr * 512 + c0 + sc);
      f32x4 a0 = src[0], a1 = src[1], a2 = src[2], a3 = src[3];
      alignas(16) u16 h[16];
      #pragma unroll
      for (int i = 0; i < 4; ++i){ h[i] = f2bf(a0[i]); h[4+i] = f2bf(a1[i]); h[8+i] = f2bf(a2[i]); h[12+i] = f2bf(a3[i]); }
      *(s16x8*)&A_lds[sr][sc]     = *(const s16x8*)&h[0];
      *(s16x8*)&A_lds[sr][sc + 8] = *(const s16x8*)&h[8];
    }
    __syncthreads();
    #pragma unroll
    for (int kk = 0; kk < 2; ++kk){
      s16x8 af[4];
      #pragma unroll
      for (int m = 0; m < 4; ++m)
        af[m] = *(const s16x8*)&A_lds[m * 16 + l15][kk * 32 + lg * 8];
      #pragma unroll
      for (int kc = 0; kc < 4; ++kc){
        s16x8 bf = *(const s16x8*)&WT_in[(size_t)(kbase + kc * 16 + l15) * 512 + c0 + kk * 32 + lg * 8];
        #pragma unroll
        for (int m = 0; m < 4; ++m) acc[m][kc] = mfma16(af[m], bf, acc[m][kc]);
      }
    }
  }

  #pragma unroll
  for (int kc = 0; kc < 4; ++kc){
    const int kglob = kbase + kc * 16 + l15;
    const float bias = b_in[kglob];
    #pragma unroll
    for (int m = 0; m < 4; ++m){
      const int posb = p0 + m * 16 + lg * 4;
      if (kt < 4){
        u16* dst = (kt < 2) ? Qp : Kp;
        const int kq = (kt < 2) ? kglob : (kglob - 512);
        uint2 pk;
        pk.x = (unsigned)f2bf(acc[m][kc][0] + bias) | ((unsigned)f2bf(acc[m][kc][1] + bias) << 16);
        pk.y = (unsigned)f2bf(acc[m][kc][2] + bias) | ((unsigned)f2bf(acc[m][kc][3] + bias) << 16);
        *(uint2*)&dst[((size_t)b * 512 + kq) * 4096 + posb] = pk;
      } else {
        const int cv = kglob - 1024;
        #pragma unroll
        for (int j = 0; j < 4; ++j)
          TV[((size_t)b * 4096 + posb + j) * 512 + cv] = f2bf(acc[m][kc][j] + bias);
      }
    }
  }
}

// ---------------------------------------------------------------------------
// K2: avg-pool over N (kernel=stride=4) on Q,K planes -> q,k planes [b][c][l*64+d]
// ---------------------------------------------------------------------------
__global__ __launch_bounds__(256) void k2_pool(
    const u16* __restrict__ Qp, const u16* __restrict__ Kp,
    u16* __restrict__ qp, u16* __restrict__ kp)
{
  const int t = blockIdx.x * 256 + threadIdx.x;     // 2*2^19 total
  const int i = t & 0x7FFFF;
  const u16* src = (t >> 19) ? Kp : Qp;
  u16* dst = (t >> 19) ? kp : qp;
  const int d8 = i & 7, lp = (i >> 3) & 15, c = (i >> 7) & 511, b = (i >> 16) & 7;
  const size_t base = ((size_t)b * 512 + c) * 4096 + lp * 256 + d8 * 8;
  float s[8] = {};
  #pragma unroll
  for (int r = 0; r < 4; ++r){
    s16x8 v = *(const s16x8*)&src[base + r * 64];
    #pragma unroll
    for (int e = 0; e < 8; ++e) s[e] += bf2f((u16)v[e]);
  }
  alignas(16) u16 h[8];
  #pragma unroll
  for (int e = 0; e < 8; ++e) h[e] = f2bf(s[e] * 0.25f);
  *(s16x8*)&dst[((size_t)b * 512 + c) * 1024 + lp * 64 + d8 * 8] = *(const s16x8*)h;
}

// ---------------------------------------------------------------------------
// K3a: S1[n,l] = sum_d Q[n,d]*k[l,d]  per (b,c).  out T1[b][n*16+l][c] bf16
// ---------------------------------------------------------------------------
__global__ __launch_bounds__(256) void k3_s1(
    const u16* __restrict__ Qp, const u16* __restrict__ kp, u16* __restrict__ T1)
{
  const int W = blockIdx.x * 4 + (threadIdx.x >> 6);
  const int b = W >> 9, c = W & 511;
  const int l = threadIdx.x & 63, l15 = l & 15, lg = l >> 4;
  const u16* Qr = Qp + ((size_t)b * 512 + c) * 4096;
  const u16* kr = kp + ((size_t)b * 512 + c) * 1024;
  f32x4 acc[4] = {};
  #pragma unroll
  for (int kk = 0; kk < 2; ++kk){
    s16x8 bf = *(const s16x8*)&kr[l15 * 64 + kk * 32 + lg * 8];   // B[d,l] = k[l][d]
    #pragma unroll
    for (int m = 0; m < 4; ++m){
      s16x8 af = *(const s16x8*)&Qr[(m * 16 + l15) * 64 + kk * 32 + lg * 8];
      acc[m] = mfma16(af, bf, acc[m]);
    }
  }
  u16* T1b = T1 + (size_t)b * 1024 * 512;
  #pragma unroll
  for (int m = 0; m < 4; ++m)
    #pragma unroll
    for (int j = 0; j < 4; ++j)
      T1b[(size_t)((m * 16 + lg * 4 + j) * 16 + l15) * 512 + c] = f2bf(acc[m][j]);
}

// K3b: S2[l,n] = sum_d q[l,d]*K[n,d] per (b,c).  out T2[b][l*64+n][c]
__global__ __launch_bounds__(256) void k3_s2(
    const u16* __restrict__ qp, const u16* __restrict__ Kp, u16* __restrict__ T2)
{
  const int W = blockIdx.x * 4 + (threadIdx.x >> 6);
  const int b = W >> 9, c = W & 511;
  const int l = threadIdx.x & 63, l15 = l & 15, lg = l >> 4;
  const u16* qr = qp + ((size_t)b * 512 + c) * 1024;
  const u16* Kr = Kp + ((size_t)b * 512 + c) * 4096;
  f32x4 acc[4] = {};
  #pragma unroll
  for (int kk = 0; kk < 2; ++kk){
    s16x8 af = *(const s16x8*)&qr[l15 * 64 + kk * 32 + lg * 8];   // A[l,d]
    #pragma unroll
    for (int nt = 0; nt < 4; ++nt){
      s16x8 bf = *(const s16x8*)&Kr[(nt * 16 + l15) * 64 + kk * 32 + lg * 8]; // B[d,n]=K[n][d]
      acc[nt] = mfma16(af, bf, acc[nt]);
    }
  }
  u16* T2b = T2 + (size_t)b * 1024 * 512;
  #pragma unroll
  for (int nt = 0; nt < 4; ++nt)
    #pragma unroll
    for (int j = 0; j < 4; ++j)
      T2b[(size_t)((lg * 4 + j) * 64 + nt * 16 + l15) * 512 + c] = f2bf(acc[nt][j]);
}

// ---------------------------------------------------------------------------
// K4: inter_last.  T:[b][pos][512] bf16 -> O:[b][k2][Pn] bf16
// LDS: exactly 64 KiB.  red/redg scratch overlaid on the P tile (time-disjoint
// phases, sync-protected).  P stored with XOR swizzle col^=(row&7)<<3 so
// GEMM2 A-frag ds_reads are ~conflict-free without padding.
// ---------------------------------------------------------------------------
__global__ __launch_bounds__(512) void k4_interlast(
    const u16* __restrict__ T, u16* __restrict__ O,
    const u16* __restrict__ WTi, const float* __restrict__ bi,
    const u16* __restrict__ WTl, const float* __restrict__ bl, const int Pn)
{
  __shared__ __align__(16) u16 smem[64 * 512];     // 65536 B exactly
  float* red  = (float*)smem;                      // [2][64][8]  (4096 B)
  float* redg = (float*)smem + 1024;               // [2][64]     (512 B)
  const int b = blockIdx.y;
  const int p0 = blockIdx.x * 64;
  const int w = threadIdx.x >> 6, l = threadIdx.x & 63;
  const int l15 = l & 15, lg = l >> 4;
  const u16* Tb = T + (size_t)b * Pn * 512;

  // GEMM1: L[pos, k]   A-frags straight from global (T is [pos][c])
  f32x4 acc[4][4] = {};
  for (int cs = 0; cs < 16; ++cs){
    const int c0 = cs * 32 + lg * 8;
    s16x8 af[4];
    #pragma unroll
    for (int pr = 0; pr < 4; ++pr)
      af[pr] = *(const s16x8*)&Tb[(size_t)(p0 + pr * 16 + l15) * 512 + c0];
    #pragma unroll
    for (int kc = 0; kc < 4; ++kc){
      s16x8 bf = *(const s16x8*)&WTi[(size_t)(w * 64 + kc * 16 + l15) * 512 + c0];
      #pragma unroll
      for (int pr = 0; pr < 4; ++pr) acc[pr][kc] = mfma16(af[pr], bf, acc[pr][kc]);
    }
  }
  #pragma unroll
  for (int kc = 0; kc < 4; ++kc){
    const float bias = bi[w * 64 + kc * 16 + l15];
    #pragma unroll
    for (int pr = 0; pr < 4; ++pr)
      #pragma unroll
      for (int j = 0; j < 4; ++j) acc[pr][kc][j] += bias;
  }
  // softmax over k=512 (16 lanes x 4 reg-tiles x 8 waves).  row = pos-in-tile.
  #pragma unroll
  for (int pr = 0; pr < 4; ++pr){
    #pragma unroll
    for (int j = 0; j < 4; ++j){
      float m = acc[pr][0][j];
      #pragma unroll
      for (int kc = 1; kc < 4; ++kc) m = fmaxf(m, acc[pr][kc][j]);
      m = fmaxf(m, __shfl_xor(m, 1));
      m = fmaxf(m, __shfl_xor(m, 2));
      m = fmaxf(m, __shfl_xor(m, 4));
      m = fmaxf(m, __shfl_xor(m, 8));
      if (l15 == 0) red[(pr * 16 + lg * 4 + j) * 8 + w] = m;
    }
  }
  __syncthreads();
  if (threadIdx.x < 64){
    float m = red[threadIdx.x * 8];
    #pragma unroll
    for (int w2 = 1; w2 < 8; ++w2) m = fmaxf(m, red[threadIdx.x * 8 + w2]);
    redg[threadIdx.x] = m;
  }
  __syncthreads();
  #pragma unroll
  for (int pr = 0; pr < 4; ++pr){
    #pragma unroll
    for (int j = 0; j < 4; ++j){
      const float gm = redg[pr * 16 + lg * 4 + j];
      float s = 0.f;
      #pragma unroll
      for (int kc = 0; kc < 4; ++kc){
        float e = __expf(acc[pr][kc][j] - gm);
        acc[pr][kc][j] = e;
        s += e;
      }
      s += __shfl_xor(s, 1);
      s += __shfl_xor(s, 2);
      s += __shfl_xor(s, 4);
      s += __shfl_xor(s, 8);
      if (l15 == 0) red[512 + (pr * 16 + lg * 4 + j) * 8 + w] = s;
    }
  }
  __syncthreads();
  if (threadIdx.x < 64){
    float s = red[512 + threadIdx.x * 8];
    #pragma unroll
    for (int w2 = 1; w2 < 8; ++w2) s += red[512 + threadIdx.x * 8 + w2];
    redg[64 + threadIdx.x] = s;
  }
  __syncthreads();
  float inv[4][4];
  #pragma unroll
  for (int pr = 0; pr < 4; ++pr)
    #pragma unroll
    for (int j = 0; j < 4; ++j) inv[pr][j] = 1.f / redg[64 + pr * 16 + lg * 4 + j];
  __syncthreads();                      // all redg reads done before P overwrites smem
  // store unnormalized exp, XOR-swizzled (normalization folded into epilogue)
  #pragma unroll
  for (int pr = 0; pr < 4; ++pr)
    #pragma unroll
    for (int j = 0; j < 4; ++j){
      const int row = pr * 16 + lg * 4 + j;
      const int sw = (row & 7) << 3;
      #pragma unroll
      for (int kc = 0; kc < 4; ++kc)
        smem[row * 512 + ((w * 64 + kc * 16 + l15) ^ sw)] = f2bf(acc[pr][kc][j]);
    }
  __syncthreads();
  // GEMM2: Z[pos, k2] = P @ W_last
  f32x4 z[4][4] = {};
  const int swr = (l15 & 7) << 3;       // row = pr*16+l15 -> row&7 = l15&7
  for (int ks = 0; ks < 16; ++ks){
    const int k0 = ks * 32 + lg * 8;
    s16x8 af[4];
    #pragma unroll
    for (int pr = 0; pr < 4; ++pr)
      af[pr] = *(const s16x8*)&smem[(pr * 16 + l15) * 512 + (k0 ^ swr)];
    #pragma unroll
    for (int kc = 0; kc < 4; ++kc){
      s16x8 bf = *(const s16x8*)&WTl[(size_t)(w * 64 + kc * 16 + l15) * 512 + k0];
      #pragma unroll
      for (int pr = 0; pr < 4; ++pr) z[pr][kc] = mfma16(af[pr], bf, z[pr][kc]);
    }
  }
  u16* Ob = O + (size_t)b * 512 * Pn;
  #pragma unroll
  for (int kc = 0; kc < 4; ++kc){
    const int k2 = w * 64 + kc * 16 + l15;
    const float bias = bl[k2];
    #pragma unroll
    for (int pr = 0; pr < 4; ++pr){
      uint2 pk;
      pk.x = (unsigned)f2bf(z[pr][kc][0] * inv[pr][0] + bias) | ((unsigned)f2bf(z[pr][kc][1] * inv[pr][1] + bias) << 16);
      pk.y = (unsigned)f2bf(z[pr][kc][2] * inv[pr][2] + bias) | ((unsigned)f2bf(z[pr][kc][3] * inv[pr][3] + bias) << 16);
      *(uint2*)&Ob[(size_t)k2 * Pn + p0 + pr * 16 + lg * 4] = pk;
    }
  }
}

// ---------------------------------------------------------------------------
// K5: qKV[l,d] = sum_n qK[l,n] * Vp[n,d]  per (b,c).  one wave per (b,c)
// ---------------------------------------------------------------------------
__global__ __launch_bounds__(256) void k5_qkv2(
    const u16* __restrict__ qK, const u16* __restrict__ Vp, u16* __restrict__ qKV)
{
  const int W = blockIdx.x * 4 + (threadIdx.x >> 6);
  const int b = W >> 9, c = W & 511;
  const int l = threadIdx.x & 63, l15 = l & 15, lg = l >> 4;
  const u16* qr = qK + ((size_t)b * 512 + c) * 1024;
  const u16* vr = Vp + ((size_t)b * 512 + c) * 4096;
  f32x4 acc[4] = {};
  #pragma unroll
  for (int kk = 0; kk < 2; ++kk){
    s16x8 af = *(const s16x8*)&qr[l15 * 64 + kk * 32 + lg * 8];   // A[l,n]
    #pragma unroll
    for (int dt = 0; dt < 4; ++dt){
      alignas(16) u16 bh[8];
      #pragma unroll
      for (int j = 0; j < 8; ++j)
        bh[j] = vr[(kk * 32 + lg * 8 + j) * 64 + dt * 16 + l15];  // B[n,d]
      acc[dt] = mfma16(af, *(const s16x8*)bh, acc[dt]);
    }
  }
  u16* dst = qKV + ((size_t)b * 512 + c) * 1024;
  #pragma unroll
  for (int dt = 0; dt < 4; ++dt)
    #pragma unroll
    for (int j = 0; j < 4; ++j)
      dst[(lg * 4 + j) * 64 + dt * 16 + l15] = f2bf(acc[dt][j]);
}

// ---------------------------------------------------------------------------
// K6: out[n,d] = sum_l Qk[n,l] * qKV[l,d]  per (b,c).  K=16 zero-padded to 32.
// OUTPUT IS FLOAT32 (reference output dtype).
// ---------------------------------------------------------------------------
__global__ __launch_bounds__(256) void k6_final(
    const u16* __restrict__ Qk, const u16* __restrict__ qKV, float* __restrict__ out)
{
  const int W = blockIdx.x * 4 + (threadIdx.x >> 6);
  const int b = W >> 9, c = W & 511;
  const int l = threadIdx.x & 63, l15 = l & 15, lg = l >> 4;
  const u16* Qr = Qk + ((size_t)b * 512 + c) * 1024;
  const u16* Vr = qKV + ((size_t)b * 512 + c) * 1024;
  s16x8 af[4] = {};
  if (lg < 2){
    #pragma unroll
    for (int m = 0; m < 4; ++m)
      af[m] = *(const s16x8*)&Qr[(m * 16 + l15) * 16 + lg * 8];   // A[n,l], k=lg*8+j<16
  }
  f32x4 acc[4][4] = {};
  #pragma unroll
  for (int dt = 0; dt < 4; ++dt){
    alignas(16) u16 bh[8] = {};
    if (lg < 2){
      #pragma unroll
      for (int j = 0; j < 8; ++j)
        bh[j] = Vr[(lg * 8 + j) * 64 + dt * 16 + l15];            // B[l,d]
    }
    s16x8 bf = *(const s16x8*)bh;
    #pragma unroll
    for (int m = 0; m < 4; ++m) acc[m][dt] = mfma16(af[m], bf, acc[m][dt]);
  }
  float* ob = out + ((size_t)b * 512 + c) * 4096;
  #pragma unroll
  for (int m = 0; m < 4; ++m)
    #pragma unroll
    for (int dt = 0; dt < 4; ++dt)
      #pragma unroll
      for (int j = 0; j < 4; ++j)
        ob[(m * 16 + lg * 4 + j) * 64 + dt * 16 + l15] = acc[m][dt][j];
}

// ---------------------------------------------------------------------------
extern "C" void kernel_launch(void* const* d_in, const int* in_sizes, int n_in,
                              void* d_out, int out_size, void* d_ws, size_t ws_size,
                              hipStream_t stream)
{
  (void)in_sizes; (void)n_in; (void)out_size; (void)ws_size;
  const float* x       = (const float*)d_in[0];
  const float* W_in    = (const float*)d_in[1];
  const float* b_in    = (const float*)d_in[2];
  const float* W_inter = (const float*)d_in[3];
  const float* b_inter = (const float*)d_in[4];
  const float* W_last  = (const float*)d_in[5];
  const float* b_last  = (const float*)d_in[6];
  float* out = (float*)d_out;            // reference output dtype = float32

  char* ws = (char*)d_ws;
  size_t off = 0;
  auto alloc = [&](size_t bytes) -> u16* {
    u16* p = (u16*)(ws + off);
    off += (bytes + 255) & ~(size_t)255;
    return p;
  };
  // live-range-aliased workspace, peak ~130.5 MB
  u16* WT_in = alloc((size_t)1536 * 512 * 2);
  u16* WTi   = alloc((size_t)512 * 512 * 2);
  u16* WTl   = alloc((size_t)512 * 512 * 2);
  u16* Qp    = alloc((size_t)8 * 512 * 4096 * 2);
  u16* Kp    = alloc((size_t)8 * 512 * 4096 * 2);
  u16* TV    = alloc((size_t)8 * 4096 * 512 * 2);
  u16* qp    = alloc((size_t)8 * 512 * 1024 * 2);
  u16* kp    = alloc((size_t)8 * 512 * 1024 * 2);
  u16* T1    = alloc((size_t)8 * 1024 * 512 * 2);
  u16* T2    = alloc((size_t)8 * 1024 * 512 * 2);
  u16* Vpp   = Qp;   // Qp dead after k3_s1
  u16* Qkp   = qp;   // qp dead after k3_s2
  u16* qKp   = TV;   // TV dead after k4c (runs first of the k4s)
  u16* qKVp  = kp;   // kp dead after k3_s1

  k0_transform<<<3072, 256, 0, stream>>>(W_in, W_inter, W_last, WT_in, WTi, WTl);
  k1_qkv<<<dim3(6, 64, 8), 256, 0, stream>>>(x, WT_in, b_in, Qp, Kp, TV);
  k2_pool<<<4096, 256, 0, stream>>>(Qp, Kp, qp, kp);
  k3_s1<<<1024, 256, 0, stream>>>(Qp, kp, T1);
  k3_s2<<<1024, 256, 0, stream>>>(qp, Kp, T2);
  k4_interlast<<<dim3(64, 8), 512, 0, stream>>>(TV, Vpp, WTi, b_inter, WTl, b_last, 4096);
  k4_interlast<<<dim3(16, 8), 512, 0, stream>>>(T1, Qkp, WTi, b_inter, WTl, b_last, 1024);
  k4_interlast<<<dim3(16, 8), 512, 0, stream>>>(T2, qKp, WTi, b_inter, WTl, b_last, 1024);
  k5_qkv2<<<1024, 256, 0, stream>>>(qKp, Vpp, qKVp);
  k6_final<<<1024, 256, 0, stream>>>(Qkp, qKVp, out);
}

// Round 3
// 499.011 us; speedup vs baseline: 1.2158x; 1.2158x over previous
//
#include <hip/hip_runtime.h>

typedef unsigned short u16;
typedef __attribute__((ext_vector_type(8))) short s16x8;
typedef __attribute__((ext_vector_type(4))) short s16x4;
typedef __attribute__((ext_vector_type(4))) float f32x4;

__device__ __forceinline__ u16 f2bf(float f){
  union { float f; unsigned u; } v; v.f = f;
  unsigned r = v.u + 0x7FFFu + ((v.u >> 16) & 1u);
  return (u16)(r >> 16);
}
__device__ __forceinline__ float bf2f(u16 h){
  union { unsigned u; float f; } v; v.u = ((unsigned)h) << 16;
  return v.f;
}
__device__ __forceinline__ f32x4 mfma16(s16x8 a, s16x8 b, f32x4 c){
  return __builtin_amdgcn_mfma_f32_16x16x32_bf16(a, b, c, 0, 0, 0);
}
__device__ __forceinline__ void gload16(const void* g, void* l){
  __builtin_amdgcn_global_load_lds((const __attribute__((address_space(1))) void*)g,
                                   (__attribute__((address_space(3))) void*)l, 16, 0, 0);
}

// ---------------------------------------------------------------------------
// K0w: weight transpose + bf16.  WT_in rows 0..1023 (Q,K only), WTi, WTl.
// ---------------------------------------------------------------------------
__global__ __launch_bounds__(256) void k0w(
    const float* __restrict__ W_in, const float* __restrict__ W_inter, const float* __restrict__ W_last,
    u16* __restrict__ WT_in, u16* __restrict__ WTi, u16* __restrict__ WTl)
{
  const int t = blockIdx.x * 256 + threadIdx.x;
  if (t < 1024 * 512){ const int k = t >> 9, c = t & 511; WT_in[t] = f2bf(W_in[c * 1536 + k]); }
  if (t < 512 * 512){ const int k = t >> 9, c = t & 511; WTi[t] = f2bf(W_inter[c * 512 + k]); WTl[t] = f2bf(W_last[c * 512 + k]); }
}

// ---------------------------------------------------------------------------
// K0x: x (f32) -> xb (bf16), 16.7M elems, 8 per thread.
// ---------------------------------------------------------------------------
__global__ __launch_bounds__(256) void k0x(const float* __restrict__ x, u16* __restrict__ xb)
{
  const int t = blockIdx.x * 256 + threadIdx.x;
  const f32x4* src = (const f32x4*)x + (size_t)t * 2;
  f32x4 a = src[0], b = src[1];
  alignas(16) u16 h[8];
  #pragma unroll
  for (int i = 0; i < 4; ++i){ h[i] = f2bf(a[i]); h[4 + i] = f2bf(b[i]); }
  *(s16x8*)&xb[(size_t)t * 8] = *(const s16x8*)h;
}

// ---------------------------------------------------------------------------
// K0b: W_vi[cin][k] = sum_c W_in[cin][1024+c] * W_inter[c][k]; stored
// transposed WT_vi[k][cin] bf16.  Blocks 0..15: GEMM (64 cin x 256 k tiles).
// Blocks 16..23: b_vi[k] = b_inter[k] + sum_c b_in[1024+c] W_inter[c][k].
// ---------------------------------------------------------------------------
__global__ __launch_bounds__(256) void k0b_wvi(
    const float* __restrict__ W_in, const float* __restrict__ W_inter,
    const u16* __restrict__ WTi, const float* __restrict__ b_in, const float* __restrict__ b_inter,
    u16* __restrict__ WT_vi, float* __restrict__ b_vi)
{
  __shared__ u16 A_lds[64][72];
  if (blockIdx.x >= 16){
    float* r = (float*)&A_lds[0][0];            // [4][64] f32 scratch
    const int k = (blockIdx.x - 16) * 64 + (threadIdx.x & 63);
    const int pt = threadIdx.x >> 6;
    float s = 0.f;
    #pragma unroll 4
    for (int c = pt * 128; c < pt * 128 + 128; ++c)
      s += b_in[1024 + c] * W_inter[c * 512 + k];
    r[pt * 64 + (threadIdx.x & 63)] = s;
    __syncthreads();
    if (pt == 0){
      const int kk = threadIdx.x;
      b_vi[k] = b_inter[k] + r[kk] + r[64 + kk] + r[128 + kk] + r[192 + kk];
    }
    return;
  }
  const int kt = blockIdx.x & 1;                 // 2 k-tiles of 256
  const int m0 = (blockIdx.x >> 1) * 64;         // 8 cin tiles
  const int tid = threadIdx.x;
  const int w = tid >> 6, l = tid & 63;
  const int l15 = l & 15, lg = l >> 4;
  const int kbase = kt * 256 + w * 64;
  f32x4 acc[4][4] = {};
  const int sr = tid >> 2, sc = (tid & 3) * 16;
  for (int c0 = 0; c0 < 512; c0 += 64){
    __syncthreads();
    {
      const f32x4* src = (const f32x4*)(W_in + (size_t)(m0 + sr) * 1536 + 1024 + c0 + sc);
      f32x4 a0 = src[0], a1 = src[1], a2 = src[2], a3 = src[3];
      alignas(16) u16 h[16];
      #pragma unroll
      for (int i = 0; i < 4; ++i){ h[i] = f2bf(a0[i]); h[4+i] = f2bf(a1[i]); h[8+i] = f2bf(a2[i]); h[12+i] = f2bf(a3[i]); }
      *(s16x8*)&A_lds[sr][sc]     = *(const s16x8*)&h[0];
      *(s16x8*)&A_lds[sr][sc + 8] = *(const s16x8*)&h[8];
    }
    __syncthreads();
    #pragma unroll
    for (int kk = 0; kk < 2; ++kk){
      s16x8 af[4];
      #pragma unroll
      for (int m = 0; m < 4; ++m)
        af[m] = *(const s16x8*)&A_lds[m * 16 + l15][kk * 32 + lg * 8];
      #pragma unroll
      for (int kc = 0; kc < 4; ++kc){
        s16x8 bf = *(const s16x8*)&WTi[(size_t)(kbase + kc * 16 + l15) * 512 + c0 + kk * 32 + lg * 8];
        #pragma unroll
        for (int m = 0; m < 4; ++m) acc[m][kc] = mfma16(af[m], bf, acc[m][kc]);
      }
    }
  }
  #pragma unroll
  for (int kc = 0; kc < 4; ++kc){
    const int k = kbase + kc * 16 + l15;
    #pragma unroll
    for (int m = 0; m < 4; ++m){
      const int cin = m0 + m * 16 + lg * 4;
      uint2 pk;
      pk.x = (unsigned)f2bf(acc[m][kc][0]) | ((unsigned)f2bf(acc[m][kc][1]) << 16);
      pk.y = (unsigned)f2bf(acc[m][kc][2]) | ((unsigned)f2bf(acc[m][kc][3]) << 16);
      *(uint2*)&WT_vi[(size_t)k * 512 + cin] = pk;
    }
  }
}

// ---------------------------------------------------------------------------
// K1: Q,K = xb @ WT_in[0:1024] + b_in.  128x128 tile, BK=64, 4 waves.
// global_load_lds staging with XOR-swizzled SOURCE; swizzled ds_read frags.
// Output: Q,K planes [b][k][4096] bf16.
// ---------------------------------------------------------------------------
__global__ __launch_bounds__(256) void k1_qk(
    const u16* __restrict__ xb, const u16* __restrict__ WT_in, const float* __restrict__ b_in,
    u16* __restrict__ Qp, u16* __restrict__ Kp)
{
  __shared__ __align__(16) u16 As[128 * 64];
  __shared__ __align__(16) u16 Bs[128 * 64];
  const int t = threadIdx.x;
  const int w = t >> 6, l = t & 63;
  const int l15 = l & 15, lg = l >> 4;
  const int wr = w >> 1, wc = w & 1;
  const size_t Mbase = (size_t)blockIdx.y * 128;
  const int Nbase = blockIdx.x * 128;

  f32x4 acc[4][4] = {};
  for (int c0 = 0; c0 < 512; c0 += 64){
    __syncthreads();
    #pragma unroll
    for (int it = 0; it < 4; ++it){
      const int g = it * 256 + t;                // 1024 granules = 128 rows x 8
      const int row = g >> 3, cc = g & 7;
      const int sc = (cc ^ (row & 7)) * 8;
      gload16(&xb[(Mbase + row) * 512 + c0 + sc], &As[g * 8]);
    }
    #pragma unroll
    for (int it = 0; it < 4; ++it){
      const int g = it * 256 + t;
      const int row = g >> 3, cc = g & 7;
      const int sc = (cc ^ (row & 7)) * 8;
      gload16(&WT_in[(size_t)(Nbase + row) * 512 + c0 + sc], &Bs[g * 8]);
    }
    __syncthreads();
    #pragma unroll
    for (int kk = 0; kk < 2; ++kk){
      s16x8 af[4], bf[4];
      #pragma unroll
      for (int m = 0; m < 4; ++m){
        const int row = wr * 64 + m * 16 + l15;
        af[m] = *(const s16x8*)&As[row * 64 + ((kk * 4 + lg) ^ (row & 7)) * 8];
      }
      #pragma unroll
      for (int n = 0; n < 4; ++n){
        const int row = wc * 64 + n * 16 + l15;
        bf[n] = *(const s16x8*)&Bs[row * 64 + ((kk * 4 + lg) ^ (row & 7)) * 8];
      }
      #pragma unroll
      for (int n = 0; n < 4; ++n)
        #pragma unroll
        for (int m = 0; m < 4; ++m) acc[m][n] = mfma16(af[m], bf[n], acc[m][n]);
    }
  }
  const int b = (int)(Mbase >> 12);
  const int ploc = ((int)Mbase & 4095) + wr * 64;
  #pragma unroll
  for (int n = 0; n < 4; ++n){
    const int kglob = Nbase + wc * 64 + n * 16 + l15;
    const float bias = b_in[kglob];
    u16* dst = (kglob < 512) ? Qp : Kp;
    const int kq = kglob & 511;
    #pragma unroll
    for (int m = 0; m < 4; ++m){
      const int p = ploc + m * 16 + lg * 4;
      uint2 pk;
      pk.x = (unsigned)f2bf(acc[m][n][0] + bias) | ((unsigned)f2bf(acc[m][n][1] + bias) << 16);
      pk.y = (unsigned)f2bf(acc[m][n][2] + bias) | ((unsigned)f2bf(acc[m][n][3] + bias) << 16);
      *(uint2*)&dst[((size_t)b * 512 + kq) * 4096 + p] = pk;
    }
  }
}

// ---------------------------------------------------------------------------
// K2: avg-pool over N (kernel=stride=4) on Q,K planes -> q,k planes [b][c][l*64+d]
// ---------------------------------------------------------------------------
__global__ __launch_bounds__(256) void k2_pool(
    const u16* __restrict__ Qp, const u16* __restrict__ Kp,
    u16* __restrict__ qp, u16* __restrict__ kp)
{
  const int t = blockIdx.x * 256 + threadIdx.x;
  const int i = t & 0x7FFFF;
  const u16* src = (t >> 19) ? Kp : Qp;
  u16* dst = (t >> 19) ? kp : qp;
  const int d8 = i & 7, lp = (i >> 3) & 15, c = (i >> 7) & 511, b = (i >> 16) & 7;
  const size_t base = ((size_t)b * 512 + c) * 4096 + lp * 256 + d8 * 8;
  float s[8] = {};
  #pragma unroll
  for (int r = 0; r < 4; ++r){
    s16x8 v = *(const s16x8*)&src[base + r * 64];
    #pragma unroll
    for (int e = 0; e < 8; ++e) s[e] += bf2f((u16)v[e]);
  }
  alignas(16) u16 h[8];
  #pragma unroll
  for (int e = 0; e < 8; ++e) h[e] = f2bf(s[e] * 0.25f);
  *(s16x8*)&dst[((size_t)b * 512 + c) * 1024 + lp * 64 + d8 * 8] = *(const s16x8*)h;
}

// ---------------------------------------------------------------------------
// K3a: S1[n,l] = sum_d Q[n,d]*k[l,d] per (b,c) -> T1[b][n*16+l][c] bf16
// ---------------------------------------------------------------------------
__global__ __launch_bounds__(256) void k3_s1(
    const u16* __restrict__ Qp, const u16* __restrict__ kp, u16* __restrict__ T1)
{
  const int W = blockIdx.x * 4 + (threadIdx.x >> 6);
  const int b = W >> 9, c = W & 511;
  const int l = threadIdx.x & 63, l15 = l & 15, lg = l >> 4;
  const u16* Qr = Qp + ((size_t)b * 512 + c) * 4096;
  const u16* kr = kp + ((size_t)b * 512 + c) * 1024;
  f32x4 acc[4] = {};
  #pragma unroll
  for (int kk = 0; kk < 2; ++kk){
    s16x8 bf = *(const s16x8*)&kr[l15 * 64 + kk * 32 + lg * 8];
    #pragma unroll
    for (int m = 0; m < 4; ++m){
      s16x8 af = *(const s16x8*)&Qr[(m * 16 + l15) * 64 + kk * 32 + lg * 8];
      acc[m] = mfma16(af, bf, acc[m]);
    }
  }
  u16* T1b = T1 + (size_t)b * 1024 * 512;
  #pragma unroll
  for (int m = 0; m < 4; ++m)
    #pragma unroll
    for (int j = 0; j < 4; ++j)
      T1b[(size_t)((m * 16 + lg * 4 + j) * 16 + l15) * 512 + c] = f2bf(acc[m][j]);
}

// K3b: S2[l,n] = sum_d q[l,d]*K[n,d] per (b,c) -> T2[b][l*64+n][c]
__global__ __launch_bounds__(256) void k3_s2(
    const u16* __restrict__ qp, const u16* __restrict__ Kp, u16* __restrict__ T2)
{
  const int W = blockIdx.x * 4 + (threadIdx.x >> 6);
  const int b = W >> 9, c = W & 511;
  const int l = threadIdx.x & 63, l15 = l & 15, lg = l >> 4;
  const u16* qr = qp + ((size_t)b * 512 + c) * 1024;
  const u16* Kr = Kp + ((size_t)b * 512 + c) * 4096;
  f32x4 acc[4] = {};
  #pragma unroll
  for (int kk = 0; kk < 2; ++kk){
    s16x8 af = *(const s16x8*)&qr[l15 * 64 + kk * 32 + lg * 8];
    #pragma unroll
    for (int nt = 0; nt < 4; ++nt){
      s16x8 bf = *(const s16x8*)&Kr[(nt * 16 + l15) * 64 + kk * 32 + lg * 8];
      acc[nt] = mfma16(af, bf, acc[nt]);
    }
  }
  u16* T2b = T2 + (size_t)b * 1024 * 512;
  #pragma unroll
  for (int nt = 0; nt < 4; ++nt)
    #pragma unroll
    for (int j = 0; j < 4; ++j)
      T2b[(size_t)((lg * 4 + j) * 64 + nt * 16 + l15) * 512 + c] = f2bf(acc[nt][j]);
}

// ---------------------------------------------------------------------------
// K4: inter_last.  A:[b][pos][512] bf16 staged to LDS (swizzled source),
// softmax over k, GEMM2, -> O:[b][k2][Pn] bf16 planes.  LDS 64 KiB exactly.
// ---------------------------------------------------------------------------
__global__ __launch_bounds__(512) void k4_interlast(
    const u16* __restrict__ T, u16* __restrict__ O,
    const u16* __restrict__ WTi, const float* __restrict__ bi,
    const u16* __restrict__ WTl, const float* __restrict__ bl, const int Pn)
{
  __shared__ __align__(16) u16 smem[64 * 512];
  float* red  = (float*)smem;
  float* redg = (float*)smem + 1024;
  const int b = blockIdx.y;
  const int p0 = blockIdx.x * 64;
  const int w = threadIdx.x >> 6, l = threadIdx.x & 63;
  const int l15 = l & 15, lg = l >> 4;
  const u16* Tb = T + (size_t)b * Pn * 512;

  // stage A tile 64x512 bf16, source-swizzled (low-3 granule bits ^ row&7)
  #pragma unroll
  for (int it = 0; it < 8; ++it){
    const int g = it * 512 + threadIdx.x;        // 4096 granules = 64 rows x 64
    const int row = g >> 6, cc = g & 63;
    const int sc = ((cc & 7) ^ (row & 7)) | (cc & 56);
    gload16(&Tb[(size_t)(p0 + row) * 512 + sc * 8], &smem[g * 8]);
  }
  __syncthreads();

  // GEMM1 from LDS (A) x global (WTi)
  f32x4 acc[4][4] = {};
  for (int cs = 0; cs < 16; ++cs){
    s16x8 af[4];
    #pragma unroll
    for (int pr = 0; pr < 4; ++pr){
      const int row = pr * 16 + l15;
      const int gi = cs * 4 + lg;
      const int gs = ((gi & 7) ^ (row & 7)) | (gi & 56);
      af[pr] = *(const s16x8*)&smem[row * 512 + gs * 8];
    }
    const int c0 = cs * 32 + lg * 8;
    #pragma unroll
    for (int kc = 0; kc < 4; ++kc){
      s16x8 bf = *(const s16x8*)&WTi[(size_t)(w * 64 + kc * 16 + l15) * 512 + c0];
      #pragma unroll
      for (int pr = 0; pr < 4; ++pr) acc[pr][kc] = mfma16(af[pr], bf, acc[pr][kc]);
    }
  }
  __syncthreads();                     // A region dead; red overlays it

  #pragma unroll
  for (int kc = 0; kc < 4; ++kc){
    const float bias = bi[w * 64 + kc * 16 + l15];
    #pragma unroll
    for (int pr = 0; pr < 4; ++pr)
      #pragma unroll
      for (int j = 0; j < 4; ++j) acc[pr][kc][j] += bias;
  }
  #pragma unroll
  for (int pr = 0; pr < 4; ++pr){
    #pragma unroll
    for (int j = 0; j < 4; ++j){
      float m = acc[pr][0][j];
      #pragma unroll
      for (int kc = 1; kc < 4; ++kc) m = fmaxf(m, acc[pr][kc][j]);
      m = fmaxf(m, __shfl_xor(m, 1));
      m = fmaxf(m, __shfl_xor(m, 2));
      m = fmaxf(m, __shfl_xor(m, 4));
      m = fmaxf(m, __shfl_xor(m, 8));
      if (l15 == 0) red[(pr * 16 + lg * 4 + j) * 8 + w] = m;
    }
  }
  __syncthreads();
  if (threadIdx.x < 64){
    float m = red[threadIdx.x * 8];
    #pragma unroll
    for (int w2 = 1; w2 < 8; ++w2) m = fmaxf(m, red[threadIdx.x * 8 + w2]);
    redg[threadIdx.x] = m;
  }
  __syncthreads();
  #pragma unroll
  for (int pr = 0; pr < 4; ++pr){
    #pragma unroll
    for (int j = 0; j < 4; ++j){
      const float gm = redg[pr * 16 + lg * 4 + j];
      float s = 0.f;
      #pragma unroll
      for (int kc = 0; kc < 4; ++kc){
        float e = __expf(acc[pr][kc][j] - gm);
        acc[pr][kc][j] = e;
        s += e;
      }
      s += __shfl_xor(s, 1);
      s += __shfl_xor(s, 2);
      s += __shfl_xor(s, 4);
      s += __shfl_xor(s, 8);
      if (l15 == 0) red[512 + (pr * 16 + lg * 4 + j) * 8 + w] = s;
    }
  }
  __syncthreads();
  if (threadIdx.x < 64){
    float s = red[512 + threadIdx.x * 8];
    #pragma unroll
    for (int w2 = 1; w2 < 8; ++w2) s += red[512 + threadIdx.x * 8 + w2];
    redg[64 + threadIdx.x] = s;
  }
  __syncthreads();
  float inv[4][4];
  #pragma unroll
  for (int pr = 0; pr < 4; ++pr)
    #pragma unroll
    for (int j = 0; j < 4; ++j) inv[pr][j] = 1.f / redg[64 + pr * 16 + lg * 4 + j];
  __syncthreads();
  // P store (unnormalized exp), element-XOR swizzle col ^ (row&7)<<3
  #pragma unroll
  for (int pr = 0; pr < 4; ++pr)
    #pragma unroll
    for (int j = 0; j < 4; ++j){
      const int row = pr * 16 + lg * 4 + j;
      const int sw = (row & 7) << 3;
      #pragma unroll
      for (int kc = 0; kc < 4; ++kc)
        smem[row * 512 + ((w * 64 + kc * 16 + l15) ^ sw)] = f2bf(acc[pr][kc][j]);
    }
  __syncthreads();
  // GEMM2: Z = P @ W_last
  f32x4 z[4][4] = {};
  const int swr = (l15 & 7) << 3;
  for (int ks = 0; ks < 16; ++ks){
    const int k0 = ks * 32 + lg * 8;
    s16x8 af[4];
    #pragma unroll
    for (int pr = 0; pr < 4; ++pr)
      af[pr] = *(const s16x8*)&smem[(pr * 16 + l15) * 512 + (k0 ^ swr)];
    #pragma unroll
    for (int kc = 0; kc < 4; ++kc){
      s16x8 bf = *(const s16x8*)&WTl[(size_t)(w * 64 + kc * 16 + l15) * 512 + k0];
      #pragma unroll
      for (int pr = 0; pr < 4; ++pr) z[pr][kc] = mfma16(af[pr], bf, z[pr][kc]);
    }
  }
  u16* Ob = O + (size_t)b * 512 * Pn;
  #pragma unroll
  for (int kc = 0; kc < 4; ++kc){
    const int k2 = w * 64 + kc * 16 + l15;
    const float bias = bl[k2];
    #pragma unroll
    for (int pr = 0; pr < 4; ++pr){
      uint2 pk;
      pk.x = (unsigned)f2bf(z[pr][kc][0] * inv[pr][0] + bias) | ((unsigned)f2bf(z[pr][kc][1] * inv[pr][1] + bias) << 16);
      pk.y = (unsigned)f2bf(z[pr][kc][2] * inv[pr][2] + bias) | ((unsigned)f2bf(z[pr][kc][3] * inv[pr][3] + bias) << 16);
      *(uint2*)&Ob[(size_t)k2 * Pn + p0 + pr * 16 + lg * 4] = pk;
    }
  }
}

// ---------------------------------------------------------------------------
// K56 (fused k5+k6): per (b,c) wave:
//   qKV[l,d] = sum_n qK[l,n] * Vp[n,d]   (V staged in LDS, pad-68 rows)
//   out[n,d] = sum_l Qk[n,l] * qKV[l,d]  (qKV transposed through 2KB LDS)
// ---------------------------------------------------------------------------
__global__ __launch_bounds__(256) void k56(
    const u16* __restrict__ qK, const u16* __restrict__ Vp, const u16* __restrict__ Qk,
    float* __restrict__ out)
{
  __shared__ __align__(16) u16 Vt[4][64 * 68];
  __shared__ __align__(16) u16 Tt[4][16 * 64];
  const int w = threadIdx.x >> 6;
  const int W = blockIdx.x * 4 + w;
  const int b = W >> 9, c = W & 511;
  const int l = threadIdx.x & 63, l15 = l & 15, lg = l >> 4;
  const u16* qr = qK + ((size_t)b * 512 + c) * 1024;
  const u16* vr = Vp + ((size_t)b * 512 + c) * 4096;
  u16* vt = &Vt[w][0];
  u16* tt = &Tt[w][0];
  { // stage V rows: lane l owns row n=l (64 d = 128B contiguous)
    const s16x8* src = (const s16x8*)&vr[l * 64];
    #pragma unroll
    for (int i = 0; i < 8; ++i){
      s16x8 v = src[i];
      *(s16x4*)&vt[l * 68 + i * 8]     = __builtin_shufflevector(v, v, 0, 1, 2, 3);
      *(s16x4*)&vt[l * 68 + i * 8 + 4] = __builtin_shufflevector(v, v, 4, 5, 6, 7);
    }
  }
  f32x4 acc1[4] = {};
  #pragma unroll
  for (int kk = 0; kk < 2; ++kk){
    s16x8 af = *(const s16x8*)&qr[l15 * 64 + kk * 32 + lg * 8];   // A[l][n]
    #pragma unroll
    for (int dt = 0; dt < 4; ++dt){
      alignas(16) u16 bh[8];
      #pragma unroll
      for (int j = 0; j < 8; ++j)
        bh[j] = vt[(kk * 32 + lg * 8 + j) * 68 + dt * 16 + l15];  // B[n][d]
      acc1[dt] = mfma16(af, *(const s16x8*)bh, acc1[dt]);
    }
  }
  // qKV -> LDS [l(16)][d(64)]
  #pragma unroll
  for (int dt = 0; dt < 4; ++dt)
    #pragma unroll
    for (int j = 0; j < 4; ++j)
      tt[(lg * 4 + j) * 64 + dt * 16 + l15] = f2bf(acc1[dt][j]);
  // MFMA2: A = Qk[n][l-slice] (K=16 zero-padded), B = qKV[l][d]
  const u16* Qr = Qk + ((size_t)b * 512 + c) * 1024;
  s16x8 af2[4] = {};
  if (lg < 2){
    #pragma unroll
    for (int m = 0; m < 4; ++m)
      af2[m] = *(const s16x8*)&Qr[(m * 16 + l15) * 16 + lg * 8];
  }
  f32x4 acc2[4][4] = {};
  #pragma unroll
  for (int dt = 0; dt < 4; ++dt){
    alignas(16) u16 bh[8] = {};
    if (lg < 2){
      #pragma unroll
      for (int j = 0; j < 8; ++j)
        bh[j] = tt[(lg * 8 + j) * 64 + dt * 16 + l15];
    }
    s16x8 bf = *(const s16x8*)bh;
    #pragma unroll
    for (int m = 0; m < 4; ++m) acc2[m][dt] = mfma16(af2[m], bf, acc2[m][dt]);
  }
  float* ob = out + ((size_t)b * 512 + c) * 4096;
  #pragma unroll
  for (int m = 0; m < 4; ++m)
    #pragma unroll
    for (int dt = 0; dt < 4; ++dt)
      #pragma unroll
      for (int j = 0; j < 4; ++j)
        ob[(m * 16 + lg * 4 + j) * 64 + dt * 16 + l15] = acc2[m][dt][j];
}

// ---------------------------------------------------------------------------
extern "C" void kernel_launch(void* const* d_in, const int* in_sizes, int n_in,
                              void* d_out, int out_size, void* d_ws, size_t ws_size,
                              hipStream_t stream)
{
  (void)in_sizes; (void)n_in; (void)out_size; (void)ws_size;
  const float* x       = (const float*)d_in[0];
  const float* W_in    = (const float*)d_in[1];
  const float* b_in    = (const float*)d_in[2];
  const float* W_inter = (const float*)d_in[3];
  const float* b_inter = (const float*)d_in[4];
  const float* W_last  = (const float*)d_in[5];
  const float* b_last  = (const float*)d_in[6];
  float* out = (float*)d_out;

  char* ws = (char*)d_ws;
  size_t off = 0;
  auto alloc = [&](size_t bytes) -> u16* {
    u16* p = (u16*)(ws + off);
    off += (bytes + 255) & ~(size_t)255;
    return p;
  };
  u16*  WT_in = alloc((size_t)1024 * 512 * 2);   // Q,K rows only
  u16*  WTi   = alloc((size_t)512 * 512 * 2);
  u16*  WTl   = alloc((size_t)512 * 512 * 2);
  u16*  WT_vi = alloc((size_t)512 * 512 * 2);
  float* b_vi = (float*)alloc((size_t)512 * 4);
  u16*  xb    = alloc((size_t)8 * 4096 * 512 * 2);
  u16*  Qp    = alloc((size_t)8 * 512 * 4096 * 2);
  u16*  Kp    = alloc((size_t)8 * 512 * 4096 * 2);
  u16*  qp    = alloc((size_t)8 * 512 * 1024 * 2);
  u16*  kp    = alloc((size_t)8 * 512 * 1024 * 2);
  u16*  T1    = alloc((size_t)8 * 1024 * 512 * 2);
  u16*  T2    = alloc((size_t)8 * 1024 * 512 * 2);
  u16*  Vpp   = Qp;   // Qp dead after k3_s1
  u16*  Qkp   = qp;   // qp dead after k3_s2
  u16*  qKp   = kp;   // kp dead after k3_s1

  k0w<<<2048, 256, 0, stream>>>(W_in, W_inter, W_last, WT_in, WTi, WTl);
  k0x<<<8192, 256, 0, stream>>>(x, xb);
  k0b_wvi<<<24, 256, 0, stream>>>(W_in, W_inter, WTi, b_in, b_inter, WT_vi, b_vi);
  k1_qk<<<dim3(8, 256), 256, 0, stream>>>(xb, WT_in, b_in, Qp, Kp);
  k2_pool<<<4096, 256, 0, stream>>>(Qp, Kp, qp, kp);
  k3_s1<<<1024, 256, 0, stream>>>(Qp, kp, T1);
  k3_s2<<<1024, 256, 0, stream>>>(qp, Kp, T2);
  k4_interlast<<<dim3(64, 8), 512, 0, stream>>>(xb, Vpp, WT_vi, b_vi, WTl, b_last, 4096);   // V path (folded)
  k4_interlast<<<dim3(16, 8), 512, 0, stream>>>(T1, Qkp, WTi, b_inter, WTl, b_last, 1024);  // Qk
  k4_interlast<<<dim3(16, 8), 512, 0, stream>>>(T2, qKp, WTi, b_inter, WTl, b_last, 1024);  // qK
  k56<<<1024, 256, 0, stream>>>(qKp, Vpp, Qkp, out);
}

// Round 4
// 387.410 us; speedup vs baseline: 1.5661x; 1.2881x over previous
//
#include <hip/hip_runtime.h>

typedef unsigned short u16;
typedef __attribute__((ext_vector_type(8))) short s16x8;
typedef __attribute__((ext_vector_type(4))) short s16x4;
typedef __attribute__((ext_vector_type(4))) float f32x4;

__device__ __forceinline__ u16 f2bf(float f){
  union { float f; unsigned u; } v; v.f = f;
  unsigned r = v.u + 0x7FFFu + ((v.u >> 16) & 1u);
  return (u16)(r >> 16);
}
__device__ __forceinline__ float bf2f(u16 h){
  union { unsigned u; float f; } v; v.u = ((unsigned)h) << 16;
  return v.f;
}
__device__ __forceinline__ f32x4 mfma16(s16x8 a, s16x8 b, f32x4 c){
  return __builtin_amdgcn_mfma_f32_16x16x32_bf16(a, b, c, 0, 0, 0);
}
__device__ __forceinline__ void gload16(const void* g, void* l){
  __builtin_amdgcn_global_load_lds((const __attribute__((address_space(1))) void*)g,
                                   (__attribute__((address_space(3))) void*)l, 16, 0, 0);
}
// frag-linear offset for W[k_out][c_in] tiles consumed as MFMA B-frags:
// tile (k>>4, c>>5) of 16k x 32c; within: lane (lg=(c>>3)&3, l15=k&15) holds 8 elems
__device__ __forceinline__ int flidx(int k, int c){
  return ((k >> 4) * 16 + (c >> 5)) * 512 + ((c >> 3) & 3) * 128 + (k & 15) * 8 + (c & 7);
}

// ---------------------------------------------------------------------------
// K0w: WT_in rows 0..1023 row-major (for k1 LDS staging); WTi row-major (for
// k0b); WiFL/WlFL frag-linear (for k4 coalesced B-frag loads).
// ---------------------------------------------------------------------------
__global__ __launch_bounds__(256) void k0w(
    const float* __restrict__ W_in, const float* __restrict__ W_inter, const float* __restrict__ W_last,
    u16* __restrict__ WT_in, u16* __restrict__ WTi_rm, u16* __restrict__ WiFL, u16* __restrict__ WlFL)
{
  const int t = blockIdx.x * 256 + threadIdx.x;
  if (t < 1024 * 512){ const int k = t >> 9, c = t & 511; WT_in[t] = f2bf(W_in[c * 1536 + k]); }
  if (t < 512 * 512){
    const int k = t >> 9, c = t & 511;
    const int fl = flidx(k, c);
    const u16 wi = f2bf(W_inter[c * 512 + k]);
    WTi_rm[t] = wi;
    WiFL[fl]  = wi;
    WlFL[fl]  = f2bf(W_last[c * 512 + k]);
  }
}

// ---------------------------------------------------------------------------
// K0x: x (f32) -> xb (bf16)
// ---------------------------------------------------------------------------
__global__ __launch_bounds__(256) void k0x(const float* __restrict__ x, u16* __restrict__ xb)
{
  const int t = blockIdx.x * 256 + threadIdx.x;
  const f32x4* src = (const f32x4*)x + (size_t)t * 2;
  f32x4 a = src[0], b = src[1];
  alignas(16) u16 h[8];
  #pragma unroll
  for (int i = 0; i < 4; ++i){ h[i] = f2bf(a[i]); h[4 + i] = f2bf(b[i]); }
  *(s16x8*)&xb[(size_t)t * 8] = *(const s16x8*)h;
}

// ---------------------------------------------------------------------------
// K0b: W_vi = W_v @ W_inter (folded V path), emitted FRAG-LINEAR (WviFL);
// b_vi = b_inter + b_v @ W_inter.
// ---------------------------------------------------------------------------
__global__ __launch_bounds__(256) void k0b_wvi(
    const float* __restrict__ W_in, const float* __restrict__ W_inter,
    const u16* __restrict__ WTi_rm, const float* __restrict__ b_in, const float* __restrict__ b_inter,
    u16* __restrict__ WviFL, float* __restrict__ b_vi)
{
  __shared__ u16 A_lds[64][72];
  if (blockIdx.x >= 16){
    float* r = (float*)&A_lds[0][0];
    const int k = (blockIdx.x - 16) * 64 + (threadIdx.x & 63);
    const int pt = threadIdx.x >> 6;
    float s = 0.f;
    #pragma unroll 4
    for (int c = pt * 128; c < pt * 128 + 128; ++c)
      s += b_in[1024 + c] * W_inter[c * 512 + k];
    r[pt * 64 + (threadIdx.x & 63)] = s;
    __syncthreads();
    if (pt == 0){
      const int kk = threadIdx.x;
      b_vi[k] = b_inter[k] + r[kk] + r[64 + kk] + r[128 + kk] + r[192 + kk];
    }
    return;
  }
  const int kt = blockIdx.x & 1;
  const int m0 = (blockIdx.x >> 1) * 64;
  const int tid = threadIdx.x;
  const int w = tid >> 6, l = tid & 63;
  const int l15 = l & 15, lg = l >> 4;
  const int kbase = kt * 256 + w * 64;
  f32x4 acc[4][4] = {};
  const int sr = tid >> 2, sc = (tid & 3) * 16;
  for (int c0 = 0; c0 < 512; c0 += 64){
    __syncthreads();
    {
      const f32x4* src = (const f32x4*)(W_in + (size_t)(m0 + sr) * 1536 + 1024 + c0 + sc);
      f32x4 a0 = src[0], a1 = src[1], a2 = src[2], a3 = src[3];
      alignas(16) u16 h[16];
      #pragma unroll
      for (int i = 0; i < 4; ++i){ h[i] = f2bf(a0[i]); h[4+i] = f2bf(a1[i]); h[8+i] = f2bf(a2[i]); h[12+i] = f2bf(a3[i]); }
      *(s16x8*)&A_lds[sr][sc]     = *(const s16x8*)&h[0];
      *(s16x8*)&A_lds[sr][sc + 8] = *(const s16x8*)&h[8];
    }
    __syncthreads();
    #pragma unroll
    for (int kk = 0; kk < 2; ++kk){
      s16x8 af[4];
      #pragma unroll
      for (int m = 0; m < 4; ++m)
        af[m] = *(const s16x8*)&A_lds[m * 16 + l15][kk * 32 + lg * 8];
      #pragma unroll
      for (int kc = 0; kc < 4; ++kc){
        s16x8 bf = *(const s16x8*)&WTi_rm[(size_t)(kbase + kc * 16 + l15) * 512 + c0 + kk * 32 + lg * 8];
        #pragma unroll
        for (int m = 0; m < 4; ++m) acc[m][kc] = mfma16(af[m], bf, acc[m][kc]);
      }
    }
  }
  #pragma unroll
  for (int kc = 0; kc < 4; ++kc){
    const int k = kbase + kc * 16 + l15;
    #pragma unroll
    for (int m = 0; m < 4; ++m){
      const int cin = m0 + m * 16 + lg * 4;   // cin%4==0, stays in one e-octet
      uint2 pk;
      pk.x = (unsigned)f2bf(acc[m][kc][0]) | ((unsigned)f2bf(acc[m][kc][1]) << 16);
      pk.y = (unsigned)f2bf(acc[m][kc][2]) | ((unsigned)f2bf(acc[m][kc][3]) << 16);
      *(uint2*)&WviFL[flidx(k, cin)] = pk;
    }
  }
}

// ---------------------------------------------------------------------------
// K1: Q,K = xb @ WT_in[0:1024] + b_in.  128x128 tile, BK=64, 4 waves,
// gload_lds staging with swizzled source.  Out: Q,K planes [b][k][4096].
// ---------------------------------------------------------------------------
__global__ __launch_bounds__(256) void k1_qk(
    const u16* __restrict__ xb, const u16* __restrict__ WT_in, const float* __restrict__ b_in,
    u16* __restrict__ Qp, u16* __restrict__ Kp)
{
  __shared__ __align__(16) u16 As[128 * 64];
  __shared__ __align__(16) u16 Bs[128 * 64];
  const int t = threadIdx.x;
  const int w = t >> 6, l = t & 63;
  const int l15 = l & 15, lg = l >> 4;
  const int wr = w >> 1, wc = w & 1;
  const size_t Mbase = (size_t)blockIdx.y * 128;
  const int Nbase = blockIdx.x * 128;

  f32x4 acc[4][4] = {};
  for (int c0 = 0; c0 < 512; c0 += 64){
    __syncthreads();
    #pragma unroll
    for (int it = 0; it < 4; ++it){
      const int g = it * 256 + t;
      const int row = g >> 3, cc = g & 7;
      const int sc = (cc ^ (row & 7)) * 8;
      gload16(&xb[(Mbase + row) * 512 + c0 + sc], &As[g * 8]);
    }
    #pragma unroll
    for (int it = 0; it < 4; ++it){
      const int g = it * 256 + t;
      const int row = g >> 3, cc = g & 7;
      const int sc = (cc ^ (row & 7)) * 8;
      gload16(&WT_in[(size_t)(Nbase + row) * 512 + c0 + sc], &Bs[g * 8]);
    }
    __syncthreads();
    #pragma unroll
    for (int kk = 0; kk < 2; ++kk){
      s16x8 af[4], bf[4];
      #pragma unroll
      for (int m = 0; m < 4; ++m){
        const int row = wr * 64 + m * 16 + l15;
        af[m] = *(const s16x8*)&As[row * 64 + ((kk * 4 + lg) ^ (row & 7)) * 8];
      }
      #pragma unroll
      for (int n = 0; n < 4; ++n){
        const int row = wc * 64 + n * 16 + l15;
        bf[n] = *(const s16x8*)&Bs[row * 64 + ((kk * 4 + lg) ^ (row & 7)) * 8];
      }
      #pragma unroll
      for (int n = 0; n < 4; ++n)
        #pragma unroll
        for (int m = 0; m < 4; ++m) acc[m][n] = mfma16(af[m], bf[n], acc[m][n]);
    }
  }
  const int b = (int)(Mbase >> 12);
  const int ploc = ((int)Mbase & 4095) + wr * 64;
  #pragma unroll
  for (int n = 0; n < 4; ++n){
    const int kglob = Nbase + wc * 64 + n * 16 + l15;
    const float bias = b_in[kglob];
    u16* dst = (kglob < 512) ? Qp : Kp;
    const int kq = kglob & 511;
    #pragma unroll
    for (int m = 0; m < 4; ++m){
      const int p = ploc + m * 16 + lg * 4;
      uint2 pk;
      pk.x = (unsigned)f2bf(acc[m][n][0] + bias) | ((unsigned)f2bf(acc[m][n][1] + bias) << 16);
      pk.y = (unsigned)f2bf(acc[m][n][2] + bias) | ((unsigned)f2bf(acc[m][n][3] + bias) << 16);
      *(uint2*)&dst[((size_t)b * 512 + kq) * 4096 + p] = pk;
    }
  }
}

// ---------------------------------------------------------------------------
// K2: avg-pool over N (k=stride=4) on Q,K planes -> q,k planes [b][c][l*64+d]
// ---------------------------------------------------------------------------
__global__ __launch_bounds__(256) void k2_pool(
    const u16* __restrict__ Qp, const u16* __restrict__ Kp,
    u16* __restrict__ qp, u16* __restrict__ kp)
{
  const int t = blockIdx.x * 256 + threadIdx.x;
  const int i = t & 0x7FFFF;
  const u16* src = (t >> 19) ? Kp : Qp;
  u16* dst = (t >> 19) ? kp : qp;
  const int d8 = i & 7, lp = (i >> 3) & 15, c = (i >> 7) & 511, b = (i >> 16) & 7;
  const size_t base = ((size_t)b * 512 + c) * 4096 + lp * 256 + d8 * 8;
  float s[8] = {};
  #pragma unroll
  for (int r = 0; r < 4; ++r){
    s16x8 v = *(const s16x8*)&src[base + r * 64];
    #pragma unroll
    for (int e = 0; e < 8; ++e) s[e] += bf2f((u16)v[e]);
  }
  alignas(16) u16 h[8];
  #pragma unroll
  for (int e = 0; e < 8; ++e) h[e] = f2bf(s[e] * 0.25f);
  *(s16x8*)&dst[((size_t)b * 512 + c) * 1024 + lp * 64 + d8 * 8] = *(const s16x8*)h;
}

// ---------------------------------------------------------------------------
// K3 (merged s1+s2): blocks 0..255 = S1 -> T12 pos 0..1023;
// 256..511 = S2 -> T12 pos 1024..2047.  16 channels/block (8 waves x 2),
// staged through padded LDS, written as coalesced 32B row-granules.
// ---------------------------------------------------------------------------
__global__ __launch_bounds__(512) void k3_scores(
    const u16* __restrict__ Qp, const u16* __restrict__ kp,
    const u16* __restrict__ qp, const u16* __restrict__ Kp,
    u16* __restrict__ T12)
{
  __shared__ __align__(16) u16 buf[1024 * 20];     // row pad 20 u16 (40 KB)
  const bool s2 = blockIdx.x >= 256;
  const int blk = blockIdx.x & 255;
  const int b = blk >> 5, c0 = (blk & 31) * 16;
  const int w = threadIdx.x >> 6;
  const int l = threadIdx.x & 63, l15 = l & 15, lg = l >> 4;
  #pragma unroll
  for (int half = 0; half < 2; ++half){
    const int c = c0 + half * 8 + w;
    const int cc = half * 8 + w;
    if (!s2){
      const u16* Qr = Qp + ((size_t)b * 512 + c) * 4096;
      const u16* kr = kp + ((size_t)b * 512 + c) * 1024;
      f32x4 acc[4] = {};
      #pragma unroll
      for (int kk = 0; kk < 2; ++kk){
        s16x8 bf = *(const s16x8*)&kr[l15 * 64 + kk * 32 + lg * 8];
        #pragma unroll
        for (int m = 0; m < 4; ++m){
          s16x8 af = *(const s16x8*)&Qr[(m * 16 + l15) * 64 + kk * 32 + lg * 8];
          acc[m] = mfma16(af, bf, acc[m]);
        }
      }
      #pragma unroll
      for (int m = 0; m < 4; ++m)
        #pragma unroll
        for (int j = 0; j < 4; ++j)
          buf[((m * 16 + lg * 4 + j) * 16 + l15) * 20 + cc] = f2bf(acc[m][j]);
    } else {
      const u16* qr = qp + ((size_t)b * 512 + c) * 1024;
      const u16* Kr = Kp + ((size_t)b * 512 + c) * 4096;
      f32x4 acc[4] = {};
      #pragma unroll
      for (int kk = 0; kk < 2; ++kk){
        s16x8 af = *(const s16x8*)&qr[l15 * 64 + kk * 32 + lg * 8];
        #pragma unroll
        for (int nt = 0; nt < 4; ++nt){
          s16x8 bf = *(const s16x8*)&Kr[(nt * 16 + l15) * 64 + kk * 32 + lg * 8];
          acc[nt] = mfma16(af, bf, acc[nt]);
        }
      }
      #pragma unroll
      for (int nt = 0; nt < 4; ++nt)
        #pragma unroll
        for (int j = 0; j < 4; ++j)
          buf[((lg * 4 + j) * 64 + nt * 16 + l15) * 20 + cc] = f2bf(acc[nt][j]);
    }
  }
  __syncthreads();
  const int off = s2 ? 1024 : 0;
  for (int rr = (int)threadIdx.x; rr < 1024; rr += 512){
    uint2 a  = *(const uint2*)&buf[rr * 20 + 0];
    uint2 bq = *(const uint2*)&buf[rr * 20 + 4];
    uint2 cq = *(const uint2*)&buf[rr * 20 + 8];
    uint2 dq = *(const uint2*)&buf[rr * 20 + 12];
    u16* dst = &T12[((size_t)b * 2048 + off + rr) * 512 + c0];
    *(uint4*)&dst[0] = make_uint4(a.x, a.y, bq.x, bq.y);
    *(uint4*)&dst[8] = make_uint4(cq.x, cq.y, dq.x, dq.y);
  }
}

// ---------------------------------------------------------------------------
// K4: inter_last.  A staged via gload_lds (swizzled source); GEMM1 B from
// frag-linear W (coalesced 1KB wave loads); NO-MAX softmax (|logits|<~3,
// shift-invariant); per-wave shfl denominator gather; GEMM2 B frag-linear;
// normalization + bias folded into epilogue.  4 barriers after GEMM1.
// ---------------------------------------------------------------------------
__global__ __launch_bounds__(512) void k4_interlast(
    const u16* __restrict__ T, u16* __restrict__ O,
    const u16* __restrict__ WiFL, const float* __restrict__ bi,
    const u16* __restrict__ WlFL, const float* __restrict__ bl, const int Pn)
{
  __shared__ __align__(16) u16 smem[64 * 512];     // 64 KiB: A, then red/P
  float* red = (float*)smem;                       // [64][8] (2 KB, overlays)
  const int b = blockIdx.y;
  const int p0 = blockIdx.x * 64;
  const int w = threadIdx.x >> 6, l = threadIdx.x & 63;
  const int l15 = l & 15, lg = l >> 4;
  const u16* Tb = T + (size_t)b * Pn * 512;

  #pragma unroll
  for (int it = 0; it < 8; ++it){
    const int g = it * 512 + threadIdx.x;
    const int row = g >> 6, cc = g & 63;
    const int sc = ((cc & 7) ^ (row & 7)) | (cc & 56);
    gload16(&Tb[(size_t)(p0 + row) * 512 + sc * 8], &smem[g * 8]);
  }
  __syncthreads();

  f32x4 acc[4][4] = {};
  for (int cs = 0; cs < 16; ++cs){
    s16x8 af[4];
    #pragma unroll
    for (int pr = 0; pr < 4; ++pr){
      const int row = pr * 16 + l15;
      const int gi = cs * 4 + lg;
      const int gs = ((gi & 7) ^ (row & 7)) | (gi & 56);
      af[pr] = *(const s16x8*)&smem[row * 512 + gs * 8];
    }
    #pragma unroll
    for (int kc = 0; kc < 4; ++kc){
      s16x8 bf = *(const s16x8*)&WiFL[(size_t)(((w * 4 + kc) * 16 + cs) * 64 + l) * 8];
      #pragma unroll
      for (int pr = 0; pr < 4; ++pr) acc[pr][kc] = mfma16(af[pr], bf, acc[pr][kc]);
    }
  }
  __syncthreads();                       // A dead

  #pragma unroll
  for (int kc = 0; kc < 4; ++kc){
    const float bias = bi[w * 64 + kc * 16 + l15];
    #pragma unroll
    for (int pr = 0; pr < 4; ++pr)
      #pragma unroll
      for (int j = 0; j < 4; ++j)
        acc[pr][kc][j] = __expf(acc[pr][kc][j] + bias);
  }
  #pragma unroll
  for (int pr = 0; pr < 4; ++pr)
    #pragma unroll
    for (int j = 0; j < 4; ++j){
      float s = (acc[pr][0][j] + acc[pr][1][j]) + (acc[pr][2][j] + acc[pr][3][j]);
      s += __shfl_xor(s, 1); s += __shfl_xor(s, 2);
      s += __shfl_xor(s, 4); s += __shfl_xor(s, 8);
      if (l15 == 0) red[(pr * 16 + lg * 4 + j) * 8 + w] = s;
    }
  __syncthreads();
  float inv[4][4];
  {
    const f32x4* r = (const f32x4*)&red[l * 8];    // lane l: denom of pos l
    f32x4 r0 = r[0], r1 = r[1];
    float S = ((r0[0] + r0[1]) + (r0[2] + r0[3])) + ((r1[0] + r1[1]) + (r1[2] + r1[3]));
    #pragma unroll
    for (int pr = 0; pr < 4; ++pr)
      #pragma unroll
      for (int j = 0; j < 4; ++j)
        inv[pr][j] = 1.f / __shfl(S, pr * 16 + lg * 4 + j);
  }
  __syncthreads();                       // red reads done before P overwrites
  #pragma unroll
  for (int pr = 0; pr < 4; ++pr)
    #pragma unroll
    for (int j = 0; j < 4; ++j){
      const int row = pr * 16 + lg * 4 + j;
      const int sw = (row & 7) << 3;
      #pragma unroll
      for (int kc = 0; kc < 4; ++kc)
        smem[row * 512 + ((w * 64 + kc * 16 + l15) ^ sw)] = f2bf(acc[pr][kc][j]);
    }
  __syncthreads();
  f32x4 z[4][4] = {};
  const int swr = (l15 & 7) << 3;
  for (int ks = 0; ks < 16; ++ks){
    const int k0 = ks * 32 + lg * 8;
    s16x8 af[4];
    #pragma unroll
    for (int pr = 0; pr < 4; ++pr)
      af[pr] = *(const s16x8*)&smem[(pr * 16 + l15) * 512 + (k0 ^ swr)];
    #pragma unroll
    for (int kc = 0; kc < 4; ++kc){
      s16x8 bf = *(const s16x8*)&WlFL[(size_t)(((w * 4 + kc) * 16 + ks) * 64 + l) * 8];
      #pragma unroll
      for (int pr = 0; pr < 4; ++pr) z[pr][kc] = mfma16(af[pr], bf, z[pr][kc]);
    }
  }
  u16* Ob = O + (size_t)b * 512 * Pn;
  #pragma unroll
  for (int kc = 0; kc < 4; ++kc){
    const int k2 = w * 64 + kc * 16 + l15;
    const float bias = bl[k2];
    #pragma unroll
    for (int pr = 0; pr < 4; ++pr){
      uint2 pk;
      pk.x = (unsigned)f2bf(z[pr][kc][0] * inv[pr][0] + bias) | ((unsigned)f2bf(z[pr][kc][1] * inv[pr][1] + bias) << 16);
      pk.y = (unsigned)f2bf(z[pr][kc][2] * inv[pr][2] + bias) | ((unsigned)f2bf(z[pr][kc][3] * inv[pr][3] + bias) << 16);
      *(uint2*)&Ob[(size_t)k2 * Pn + p0 + pr * 16 + lg * 4] = pk;
    }
  }
}

// ---------------------------------------------------------------------------
// K56 (fused): per (b,c) wave: qKV = qK @ Vp ; out = Qk @ qKV.
// Qk/qK read from merged O12 planes (row stride 2048; qK at col offset 1024).
// ---------------------------------------------------------------------------
__global__ __launch_bounds__(256) void k56(
    const u16* __restrict__ O12, const u16* __restrict__ Vp, float* __restrict__ out)
{
  __shared__ __align__(16) u16 Vt[4][64 * 68];
  __shared__ __align__(16) u16 Tt[4][16 * 64];
  const int w = threadIdx.x >> 6;
  const int W = blockIdx.x * 4 + w;
  const int b = W >> 9, c = W & 511;
  const int l = threadIdx.x & 63, l15 = l & 15, lg = l >> 4;
  const u16* base = O12 + ((size_t)b * 512 + c) * 2048;
  const u16* Qr = base;            // Qk [n][l] (pos = n*16+l)
  const u16* qr = base + 1024;     // qK [l][n] (pos = l*64+n)
  const u16* vr = Vp + ((size_t)b * 512 + c) * 4096;
  u16* vt = &Vt[w][0];
  u16* tt = &Tt[w][0];
  {
    const s16x8* src = (const s16x8*)&vr[l * 64];
    #pragma unroll
    for (int i = 0; i < 8; ++i){
      s16x8 v = src[i];
      *(s16x4*)&vt[l * 68 + i * 8]     = __builtin_shufflevector(v, v, 0, 1, 2, 3);
      *(s16x4*)&vt[l * 68 + i * 8 + 4] = __builtin_shufflevector(v, v, 4, 5, 6, 7);
    }
  }
  f32x4 acc1[4] = {};
  #pragma unroll
  for (int kk = 0; kk < 2; ++kk){
    s16x8 af = *(const s16x8*)&qr[l15 * 64 + kk * 32 + lg * 8];
    #pragma unroll
    for (int dt = 0; dt < 4; ++dt){
      alignas(16) u16 bh[8];
      #pragma unroll
      for (int j = 0; j < 8; ++j)
        bh[j] = vt[(kk * 32 + lg * 8 + j) * 68 + dt * 16 + l15];
      acc1[dt] = mfma16(af, *(const s16x8*)bh, acc1[dt]);
    }
  }
  #pragma unroll
  for (int dt = 0; dt < 4; ++dt)
    #pragma unroll
    for (int j = 0; j < 4; ++j)
      tt[(lg * 4 + j) * 64 + dt * 16 + l15] = f2bf(acc1[dt][j]);
  s16x8 af2[4] = {};
  if (lg < 2){
    #pragma unroll
    for (int m = 0; m < 4; ++m)
      af2[m] = *(const s16x8*)&Qr[(m * 16 + l15) * 16 + lg * 8];
  }
  f32x4 acc2[4][4] = {};
  #pragma unroll
  for (int dt = 0; dt < 4; ++dt){
    alignas(16) u16 bh[8] = {};
    if (lg < 2){
      #pragma unroll
      for (int j = 0; j < 8; ++j)
        bh[j] = tt[(lg * 8 + j) * 64 + dt * 16 + l15];
    }
    s16x8 bf = *(const s16x8*)bh;
    #pragma unroll
    for (int m = 0; m < 4; ++m) acc2[m][dt] = mfma16(af2[m], bf, acc2[m][dt]);
  }
  float* ob = out + ((size_t)b * 512 + c) * 4096;
  #pragma unroll
  for (int m = 0; m < 4; ++m)
    #pragma unroll
    for (int dt = 0; dt < 4; ++dt)
      #pragma unroll
      for (int j = 0; j < 4; ++j)
        ob[(m * 16 + lg * 4 + j) * 64 + dt * 16 + l15] = acc2[m][dt][j];
}

// ---------------------------------------------------------------------------
extern "C" void kernel_launch(void* const* d_in, const int* in_sizes, int n_in,
                              void* d_out, int out_size, void* d_ws, size_t ws_size,
                              hipStream_t stream)
{
  (void)in_sizes; (void)n_in; (void)out_size; (void)ws_size;
  const float* x       = (const float*)d_in[0];
  const float* W_in    = (const float*)d_in[1];
  const float* b_in    = (const float*)d_in[2];
  const float* W_inter = (const float*)d_in[3];
  const float* b_inter = (const float*)d_in[4];
  const float* W_last  = (const float*)d_in[5];
  const float* b_last  = (const float*)d_in[6];
  float* out = (float*)d_out;

  char* ws = (char*)d_ws;
  size_t off = 0;
  auto alloc = [&](size_t bytes) -> u16* {
    u16* p = (u16*)(ws + off);
    off += (bytes + 255) & ~(size_t)255;
    return p;
  };
  u16*  WT_in  = alloc((size_t)1024 * 512 * 2);
  u16*  WTi_rm = alloc((size_t)512 * 512 * 2);
  u16*  WiFL   = alloc((size_t)512 * 512 * 2);
  u16*  WlFL   = alloc((size_t)512 * 512 * 2);
  u16*  WviFL  = alloc((size_t)512 * 512 * 2);
  float* b_vi  = (float*)alloc((size_t)512 * 4);
  u16*  xb     = alloc((size_t)8 * 4096 * 512 * 2);
  u16*  Qp     = alloc((size_t)8 * 512 * 4096 * 2);
  u16*  Kp     = alloc((size_t)8 * 512 * 4096 * 2);
  u16*  qp     = alloc((size_t)8 * 512 * 1024 * 2);
  u16*  kp     = alloc((size_t)8 * 512 * 1024 * 2);
  u16*  T12    = alloc((size_t)8 * 2048 * 512 * 2);
  u16*  Vpp    = Qp;    // Qp dead after k3 (s1 reads it)
  u16*  O12    = xb;    // xb dead after k4V

  k0w<<<2048, 256, 0, stream>>>(W_in, W_inter, W_last, WT_in, WTi_rm, WiFL, WlFL);
  k0x<<<8192, 256, 0, stream>>>(x, xb);
  k0b_wvi<<<24, 256, 0, stream>>>(W_in, W_inter, WTi_rm, b_in, b_inter, WviFL, b_vi);
  k1_qk<<<dim3(8, 256), 256, 0, stream>>>(xb, WT_in, b_in, Qp, Kp);
  k2_pool<<<4096, 256, 0, stream>>>(Qp, Kp, qp, kp);
  k3_scores<<<512, 512, 0, stream>>>(Qp, kp, qp, Kp, T12);
  k4_interlast<<<dim3(64, 8), 512, 0, stream>>>(xb, Vpp, WviFL, b_vi, WlFL, b_last, 4096);
  k4_interlast<<<dim3(32, 8), 512, 0, stream>>>(T12, O12, WiFL, b_inter, WlFL, b_last, 2048);
  k56<<<1024, 256, 0, stream>>>(O12, Vpp, out);
}

// Round 5
// 353.383 us; speedup vs baseline: 1.7169x; 1.0963x over previous
//
#include <hip/hip_runtime.h>

typedef unsigned short u16;
typedef __attribute__((ext_vector_type(8))) short s16x8;
typedef __attribute__((ext_vector_type(4))) short s16x4;
typedef __attribute__((ext_vector_type(4))) float f32x4;

__device__ __forceinline__ u16 f2bf(float f){
  union { float f; unsigned u; } v; v.f = f;
  unsigned r = v.u + 0x7FFFu + ((v.u >> 16) & 1u);
  return (u16)(r >> 16);
}
__device__ __forceinline__ float bf2f(u16 h){
  union { unsigned u; float f; } v; v.u = ((unsigned)h) << 16;
  return v.f;
}
__device__ __forceinline__ f32x4 mfma16(s16x8 a, s16x8 b, f32x4 c){
  return __builtin_amdgcn_mfma_f32_16x16x32_bf16(a, b, c, 0, 0, 0);
}
__device__ __forceinline__ void gload16(const void* g, void* l){
  __builtin_amdgcn_global_load_lds((const __attribute__((address_space(1))) void*)g,
                                   (__attribute__((address_space(3))) void*)l, 16, 0, 0);
}
// frag-linear offset for W[k_out][c_in] consumed as MFMA B-frags
__device__ __forceinline__ int flidx(int k, int c){
  return ((k >> 4) * 16 + (c >> 5)) * 512 + ((c >> 3) & 3) * 128 + (k & 15) * 8 + (c & 7);
}

// ---------------------------------------------------------------------------
// K0prep (merged k0w + k0x): blocks 0..2047 = weight transform;
// blocks 2048..10239 = x f32 -> bf16.
// ---------------------------------------------------------------------------
__global__ __launch_bounds__(256) void k0prep(
    const float* __restrict__ W_in, const float* __restrict__ W_inter, const float* __restrict__ W_last,
    u16* __restrict__ WT_in, u16* __restrict__ WTi_rm, u16* __restrict__ WiFL, u16* __restrict__ WlFL,
    const float* __restrict__ x, u16* __restrict__ xb)
{
  if (blockIdx.x < 2048){
    const int t = blockIdx.x * 256 + threadIdx.x;
    if (t < 1024 * 512){ const int k = t >> 9, c = t & 511; WT_in[t] = f2bf(W_in[c * 1536 + k]); }
    if (t < 512 * 512){
      const int k = t >> 9, c = t & 511;
      const int fl = flidx(k, c);
      const u16 wi = f2bf(W_inter[c * 512 + k]);
      WTi_rm[t] = wi;
      WiFL[fl]  = wi;
      WlFL[fl]  = f2bf(W_last[c * 512 + k]);
    }
  } else {
    const int t = (blockIdx.x - 2048) * 256 + threadIdx.x;
    const f32x4* src = (const f32x4*)x + (size_t)t * 2;
    f32x4 a = src[0], b = src[1];
    alignas(16) u16 h[8];
    #pragma unroll
    for (int i = 0; i < 4; ++i){ h[i] = f2bf(a[i]); h[4 + i] = f2bf(b[i]); }
    *(s16x8*)&xb[(size_t)t * 8] = *(const s16x8*)h;
  }
}

// ---------------------------------------------------------------------------
// K0b: W_vi = W_v @ W_inter (folded V path) -> frag-linear WviFL;
// b_vi = b_inter + b_v @ W_inter.
// ---------------------------------------------------------------------------
__global__ __launch_bounds__(256) void k0b_wvi(
    const float* __restrict__ W_in, const float* __restrict__ W_inter,
    const u16* __restrict__ WTi_rm, const float* __restrict__ b_in, const float* __restrict__ b_inter,
    u16* __restrict__ WviFL, float* __restrict__ b_vi)
{
  __shared__ u16 A_lds[64][72];
  if (blockIdx.x >= 16){
    float* r = (float*)&A_lds[0][0];
    const int k = (blockIdx.x - 16) * 64 + (threadIdx.x & 63);
    const int pt = threadIdx.x >> 6;
    float s = 0.f;
    #pragma unroll 4
    for (int c = pt * 128; c < pt * 128 + 128; ++c)
      s += b_in[1024 + c] * W_inter[c * 512 + k];
    r[pt * 64 + (threadIdx.x & 63)] = s;
    __syncthreads();
    if (pt == 0){
      const int kk = threadIdx.x;
      b_vi[k] = b_inter[k] + r[kk] + r[64 + kk] + r[128 + kk] + r[192 + kk];
    }
    return;
  }
  const int kt = blockIdx.x & 1;
  const int m0 = (blockIdx.x >> 1) * 64;
  const int tid = threadIdx.x;
  const int w = tid >> 6, l = tid & 63;
  const int l15 = l & 15, lg = l >> 4;
  const int kbase = kt * 256 + w * 64;
  f32x4 acc[4][4] = {};
  const int sr = tid >> 2, sc = (tid & 3) * 16;
  for (int c0 = 0; c0 < 512; c0 += 64){
    __syncthreads();
    {
      const f32x4* src = (const f32x4*)(W_in + (size_t)(m0 + sr) * 1536 + 1024 + c0 + sc);
      f32x4 a0 = src[0], a1 = src[1], a2 = src[2], a3 = src[3];
      alignas(16) u16 h[16];
      #pragma unroll
      for (int i = 0; i < 4; ++i){ h[i] = f2bf(a0[i]); h[4+i] = f2bf(a1[i]); h[8+i] = f2bf(a2[i]); h[12+i] = f2bf(a3[i]); }
      *(s16x8*)&A_lds[sr][sc]     = *(const s16x8*)&h[0];
      *(s16x8*)&A_lds[sr][sc + 8] = *(const s16x8*)&h[8];
    }
    __syncthreads();
    #pragma unroll
    for (int kk = 0; kk < 2; ++kk){
      s16x8 af[4];
      #pragma unroll
      for (int m = 0; m < 4; ++m)
        af[m] = *(const s16x8*)&A_lds[m * 16 + l15][kk * 32 + lg * 8];
      #pragma unroll
      for (int kc = 0; kc < 4; ++kc){
        s16x8 bf = *(const s16x8*)&WTi_rm[(size_t)(kbase + kc * 16 + l15) * 512 + c0 + kk * 32 + lg * 8];
        #pragma unroll
        for (int m = 0; m < 4; ++m) acc[m][kc] = mfma16(af[m], bf, acc[m][kc]);
      }
    }
  }
  #pragma unroll
  for (int kc = 0; kc < 4; ++kc){
    const int k = kbase + kc * 16 + l15;
    #pragma unroll
    for (int m = 0; m < 4; ++m){
      const int cin = m0 + m * 16 + lg * 4;
      uint2 pk;
      pk.x = (unsigned)f2bf(acc[m][kc][0]) | ((unsigned)f2bf(acc[m][kc][1]) << 16);
      pk.y = (unsigned)f2bf(acc[m][kc][2]) | ((unsigned)f2bf(acc[m][kc][3]) << 16);
      *(uint2*)&WviFL[flidx(k, cin)] = pk;
    }
  }
}

// ---------------------------------------------------------------------------
// K1: Q,K = xb @ WT_in[0:1024] + b_in.  128x128 tile, BK=64, 4 waves,
// gload_lds staging with swizzled source.  Out: Q,K planes [b][k][4096].
// ---------------------------------------------------------------------------
__global__ __launch_bounds__(256) void k1_qk(
    const u16* __restrict__ xb, const u16* __restrict__ WT_in, const float* __restrict__ b_in,
    u16* __restrict__ Qp, u16* __restrict__ Kp)
{
  __shared__ __align__(16) u16 As[128 * 64];
  __shared__ __align__(16) u16 Bs[128 * 64];
  const int t = threadIdx.x;
  const int w = t >> 6, l = t & 63;
  const int l15 = l & 15, lg = l >> 4;
  const int wr = w >> 1, wc = w & 1;
  const size_t Mbase = (size_t)blockIdx.y * 128;
  const int Nbase = blockIdx.x * 128;

  f32x4 acc[4][4] = {};
  for (int c0 = 0; c0 < 512; c0 += 64){
    __syncthreads();
    #pragma unroll
    for (int it = 0; it < 4; ++it){
      const int g = it * 256 + t;
      const int row = g >> 3, cc = g & 7;
      const int sc = (cc ^ (row & 7)) * 8;
      gload16(&xb[(Mbase + row) * 512 + c0 + sc], &As[g * 8]);
    }
    #pragma unroll
    for (int it = 0; it < 4; ++it){
      const int g = it * 256 + t;
      const int row = g >> 3, cc = g & 7;
      const int sc = (cc ^ (row & 7)) * 8;
      gload16(&WT_in[(size_t)(Nbase + row) * 512 + c0 + sc], &Bs[g * 8]);
    }
    __syncthreads();
    #pragma unroll
    for (int kk = 0; kk < 2; ++kk){
      s16x8 af[4], bf[4];
      #pragma unroll
      for (int m = 0; m < 4; ++m){
        const int row = wr * 64 + m * 16 + l15;
        af[m] = *(const s16x8*)&As[row * 64 + ((kk * 4 + lg) ^ (row & 7)) * 8];
      }
      #pragma unroll
      for (int n = 0; n < 4; ++n){
        const int row = wc * 64 + n * 16 + l15;
        bf[n] = *(const s16x8*)&Bs[row * 64 + ((kk * 4 + lg) ^ (row & 7)) * 8];
      }
      #pragma unroll
      for (int n = 0; n < 4; ++n)
        #pragma unroll
        for (int m = 0; m < 4; ++m) acc[m][n] = mfma16(af[m], bf[n], acc[m][n]);
    }
  }
  const int b = (int)(Mbase >> 12);
  const int ploc = ((int)Mbase & 4095) + wr * 64;
  #pragma unroll
  for (int n = 0; n < 4; ++n){
    const int kglob = Nbase + wc * 64 + n * 16 + l15;
    const float bias = b_in[kglob];
    u16* dst = (kglob < 512) ? Qp : Kp;
    const int kq = kglob & 511;
    #pragma unroll
    for (int m = 0; m < 4; ++m){
      const int p = ploc + m * 16 + lg * 4;
      uint2 pk;
      pk.x = (unsigned)f2bf(acc[m][n][0] + bias) | ((unsigned)f2bf(acc[m][n][1] + bias) << 16);
      pk.y = (unsigned)f2bf(acc[m][n][2] + bias) | ((unsigned)f2bf(acc[m][n][3] + bias) << 16);
      *(uint2*)&dst[((size_t)b * 512 + kq) * 4096 + p] = pk;
    }
  }
}

// ---------------------------------------------------------------------------
// K3 (s1+s2, pooling INLINED — k2 deleted): blocks 0..255 = S1 (pos 0..1023),
// 256..511 = S2 (pos 1024..2047).  16 channels/block (8 waves x 2 halves).
// Pooled q/k frags computed on the fly: avg of 4 vector loads from Q/K plane.
// Output staged in padded LDS, written as coalesced 32B granules.
// ---------------------------------------------------------------------------
__global__ __launch_bounds__(512) void k3_scores(
    const u16* __restrict__ Qp, const u16* __restrict__ Kp, u16* __restrict__ T12)
{
  __shared__ __align__(16) u16 buf[1024 * 20];     // 40 KB
  const bool s2 = blockIdx.x >= 256;
  const int blk = blockIdx.x & 255;
  const int b = blk >> 5, c0 = (blk & 31) * 16;
  const int w = threadIdx.x >> 6;
  const int l = threadIdx.x & 63, l15 = l & 15, lg = l >> 4;
  #pragma unroll
  for (int half = 0; half < 2; ++half){
    const int c = c0 + half * 8 + w;
    const int ci = half * 8 + w;
    const u16* Qr = Qp + ((size_t)b * 512 + c) * 4096;
    const u16* Kr = Kp + ((size_t)b * 512 + c) * 4096;
    if (!s2){
      // S1[n,l] = sum_d Q[n,d] * kbar[l,d]
      f32x4 acc[4] = {};
      #pragma unroll
      for (int kk = 0; kk < 2; ++kk){
        float pv[8] = {};
        #pragma unroll
        for (int r = 0; r < 4; ++r){
          s16x8 v = *(const s16x8*)&Kr[(4 * l15 + r) * 64 + kk * 32 + lg * 8];
          #pragma unroll
          for (int j = 0; j < 8; ++j) pv[j] += bf2f((u16)v[j]);
        }
        alignas(16) u16 bh[8];
        #pragma unroll
        for (int j = 0; j < 8; ++j) bh[j] = f2bf(pv[j] * 0.25f);
        s16x8 bf = *(const s16x8*)bh;
        #pragma unroll
        for (int m = 0; m < 4; ++m){
          s16x8 af = *(const s16x8*)&Qr[(m * 16 + l15) * 64 + kk * 32 + lg * 8];
          acc[m] = mfma16(af, bf, acc[m]);
        }
      }
      #pragma unroll
      for (int m = 0; m < 4; ++m)
        #pragma unroll
        for (int j = 0; j < 4; ++j)
          buf[((m * 16 + lg * 4 + j) * 16 + l15) * 20 + ci] = f2bf(acc[m][j]);
    } else {
      // S2[l,n] = sum_d qbar[l,d] * K[n,d]
      f32x4 acc[4] = {};
      #pragma unroll
      for (int kk = 0; kk < 2; ++kk){
        float pv[8] = {};
        #pragma unroll
        for (int r = 0; r < 4; ++r){
          s16x8 v = *(const s16x8*)&Qr[(4 * l15 + r) * 64 + kk * 32 + lg * 8];
          #pragma unroll
          for (int j = 0; j < 8; ++j) pv[j] += bf2f((u16)v[j]);
        }
        alignas(16) u16 ah[8];
        #pragma unroll
        for (int j = 0; j < 8; ++j) ah[j] = f2bf(pv[j] * 0.25f);
        s16x8 af = *(const s16x8*)ah;
        #pragma unroll
        for (int nt = 0; nt < 4; ++nt){
          s16x8 bf = *(const s16x8*)&Kr[(nt * 16 + l15) * 64 + kk * 32 + lg * 8];
          acc[nt] = mfma16(af, bf, acc[nt]);
        }
      }
      #pragma unroll
      for (int nt = 0; nt < 4; ++nt)
        #pragma unroll
        for (int j = 0; j < 4; ++j)
          buf[((lg * 4 + j) * 64 + nt * 16 + l15) * 20 + ci] = f2bf(acc[nt][j]);
    }
  }
  __syncthreads();
  const int off = s2 ? 1024 : 0;
  for (int rr = (int)threadIdx.x; rr < 1024; rr += 512){
    uint2 a  = *(const uint2*)&buf[rr * 20 + 0];
    uint2 bq = *(const uint2*)&buf[rr * 20 + 4];
    uint2 cq = *(const uint2*)&buf[rr * 20 + 8];
    uint2 dq = *(const uint2*)&buf[rr * 20 + 12];
    u16* dst = &T12[((size_t)b * 2048 + off + rr) * 512 + c0];
    *(uint4*)&dst[0] = make_uint4(a.x, a.y, bq.x, bq.y);
    *(uint4*)&dst[8] = make_uint4(cq.x, cq.y, dq.x, dq.y);
  }
}

// ---------------------------------------------------------------------------
// K4 (merged V + ab): blocks x<64 = V path (T=xb, W1=WviFL, Pn=4096);
// x>=64 = ab path (T=T12, W1=WiFL, Pn=2048).  3 barriers, separate 2KB red
// LDS (66KB total, still 2 blocks/CU), 1-deep B-frag prefetch in both GEMMs,
// NO-MAX softmax, normalization folded into epilogue.
// ---------------------------------------------------------------------------
__global__ __launch_bounds__(512) void k4_interlast(
    const u16* __restrict__ TV, const u16* __restrict__ Tab,
    u16* __restrict__ OV, u16* __restrict__ Oab,
    const u16* __restrict__ WviFL, const float* __restrict__ b_vi,
    const u16* __restrict__ WiFL, const float* __restrict__ b_ab,
    const u16* __restrict__ WlFL, const float* __restrict__ bl)
{
  __shared__ __align__(16) u16 smem[64 * 512];     // A tile, then P tile
  __shared__ __align__(16) float red2[64 * 8];     // partial denominators
  const bool isV = blockIdx.x < 64;
  const int bx = isV ? (int)blockIdx.x : (int)blockIdx.x - 64;
  const int Pn = isV ? 4096 : 2048;
  const u16* T = isV ? TV : Tab;
  u16* O = isV ? OV : Oab;
  const u16* W1 = isV ? WviFL : WiFL;
  const float* bi = isV ? b_vi : b_ab;
  const int b = blockIdx.y;
  const int p0 = bx * 64;
  const int w = threadIdx.x >> 6, l = threadIdx.x & 63;
  const int l15 = l & 15, lg = l >> 4;
  const u16* Tb = T + (size_t)b * Pn * 512;

  #pragma unroll
  for (int it = 0; it < 8; ++it){
    const int g = it * 512 + threadIdx.x;
    const int row = g >> 6, cc = g & 63;
    const int sc = ((cc & 7) ^ (row & 7)) | (cc & 56);
    gload16(&Tb[(size_t)(p0 + row) * 512 + sc * 8], &smem[g * 8]);
  }
  __syncthreads();                                 // bar1: A staged

  f32x4 acc[4][4] = {};
  {
    s16x8 bfn[4];
    #pragma unroll
    for (int kc = 0; kc < 4; ++kc)
      bfn[kc] = *(const s16x8*)&W1[(size_t)(((w * 4 + kc) * 16) * 64 + l) * 8];
    for (int cs = 0; cs < 16; ++cs){
      s16x8 bfc[4];
      #pragma unroll
      for (int kc = 0; kc < 4; ++kc) bfc[kc] = bfn[kc];
      if (cs < 15){
        #pragma unroll
        for (int kc = 0; kc < 4; ++kc)
          bfn[kc] = *(const s16x8*)&W1[(size_t)(((w * 4 + kc) * 16 + cs + 1) * 64 + l) * 8];
      }
      s16x8 af[4];
      #pragma unroll
      for (int pr = 0; pr < 4; ++pr){
        const int row = pr * 16 + l15;
        const int gi = cs * 4 + lg;
        const int gs = ((gi & 7) ^ (row & 7)) | (gi & 56);
        af[pr] = *(const s16x8*)&smem[row * 512 + gs * 8];
      }
      #pragma unroll
      for (int kc = 0; kc < 4; ++kc)
        #pragma unroll
        for (int pr = 0; pr < 4; ++pr) acc[pr][kc] = mfma16(af[pr], bfc[kc], acc[pr][kc]);
    }
  }
  __syncthreads();                                 // bar2: A dead

  #pragma unroll
  for (int kc = 0; kc < 4; ++kc){
    const float bias = bi[w * 64 + kc * 16 + l15];
    #pragma unroll
    for (int pr = 0; pr < 4; ++pr)
      #pragma unroll
      for (int j = 0; j < 4; ++j)
        acc[pr][kc][j] = __expf(acc[pr][kc][j] + bias);
  }
  #pragma unroll
  for (int pr = 0; pr < 4; ++pr)
    #pragma unroll
    for (int j = 0; j < 4; ++j){
      float s = (acc[pr][0][j] + acc[pr][1][j]) + (acc[pr][2][j] + acc[pr][3][j]);
      s += __shfl_xor(s, 1); s += __shfl_xor(s, 2);
      s += __shfl_xor(s, 4); s += __shfl_xor(s, 8);
      if (l15 == 0) red2[(pr * 16 + lg * 4 + j) * 8 + w] = s;
    }
  #pragma unroll
  for (int pr = 0; pr < 4; ++pr)
    #pragma unroll
    for (int j = 0; j < 4; ++j){
      const int row = pr * 16 + lg * 4 + j;
      const int sw = (row & 7) << 3;
      #pragma unroll
      for (int kc = 0; kc < 4; ++kc)
        smem[row * 512 + ((w * 64 + kc * 16 + l15) ^ sw)] = f2bf(acc[pr][kc][j]);
    }
  __syncthreads();                                 // bar3: red + P complete

  float inv[4][4];
  {
    const f32x4* r = (const f32x4*)&red2[l * 8];   // lane l: denom of pos l
    f32x4 r0 = r[0], r1 = r[1];
    float S = ((r0[0] + r0[1]) + (r0[2] + r0[3])) + ((r1[0] + r1[1]) + (r1[2] + r1[3]));
    #pragma unroll
    for (int pr = 0; pr < 4; ++pr)
      #pragma unroll
      for (int j = 0; j < 4; ++j)
        inv[pr][j] = 1.f / __shfl(S, pr * 16 + lg * 4 + j);
  }
  f32x4 z[4][4] = {};
  {
    const int swr = (l15 & 7) << 3;
    s16x8 bfn[4];
    #pragma unroll
    for (int kc = 0; kc < 4; ++kc)
      bfn[kc] = *(const s16x8*)&WlFL[(size_t)(((w * 4 + kc) * 16) * 64 + l) * 8];
    for (int ks = 0; ks < 16; ++ks){
      s16x8 bfc[4];
      #pragma unroll
      for (int kc = 0; kc < 4; ++kc) bfc[kc] = bfn[kc];
      if (ks < 15){
        #pragma unroll
        for (int kc = 0; kc < 4; ++kc)
          bfn[kc] = *(const s16x8*)&WlFL[(size_t)(((w * 4 + kc) * 16 + ks + 1) * 64 + l) * 8];
      }
      const int k0 = ks * 32 + lg * 8;
      s16x8 af[4];
      #pragma unroll
      for (int pr = 0; pr < 4; ++pr)
        af[pr] = *(const s16x8*)&smem[(pr * 16 + l15) * 512 + (k0 ^ swr)];
      #pragma unroll
      for (int kc = 0; kc < 4; ++kc)
        #pragma unroll
        for (int pr = 0; pr < 4; ++pr) z[pr][kc] = mfma16(af[pr], bfc[kc], z[pr][kc]);
    }
  }
  u16* Ob = O + (size_t)b * 512 * Pn;
  #pragma unroll
  for (int kc = 0; kc < 4; ++kc){
    const int k2 = w * 64 + kc * 16 + l15;
    const float bias = bl[k2];
    #pragma unroll
    for (int pr = 0; pr < 4; ++pr){
      uint2 pk;
      pk.x = (unsigned)f2bf(z[pr][kc][0] * inv[pr][0] + bias) | ((unsigned)f2bf(z[pr][kc][1] * inv[pr][1] + bias) << 16);
      pk.y = (unsigned)f2bf(z[pr][kc][2] * inv[pr][2] + bias) | ((unsigned)f2bf(z[pr][kc][3] * inv[pr][3] + bias) << 16);
      *(uint2*)&Ob[(size_t)k2 * Pn + p0 + pr * 16 + lg * 4] = pk;
    }
  }
}

// ---------------------------------------------------------------------------
// K56 (fused): per (b,c) wave: qKV = qK @ Vp ; out = Qk @ qKV.
// ---------------------------------------------------------------------------
__global__ __launch_bounds__(256) void k56(
    const u16* __restrict__ O12, const u16* __restrict__ Vp, float* __restrict__ out)
{
  __shared__ __align__(16) u16 Vt[4][64 * 68];
  __shared__ __align__(16) u16 Tt[4][16 * 64];
  const int w = threadIdx.x >> 6;
  const int W = blockIdx.x * 4 + w;
  const int b = W >> 9, c = W & 511;
  const int l = threadIdx.x & 63, l15 = l & 15, lg = l >> 4;
  const u16* base = O12 + ((size_t)b * 512 + c) * 2048;
  const u16* Qr = base;            // Qk [n][l]
  const u16* qr = base + 1024;     // qK [l][n]
  const u16* vr = Vp + ((size_t)b * 512 + c) * 4096;
  u16* vt = &Vt[w][0];
  u16* tt = &Tt[w][0];
  {
    const s16x8* src = (const s16x8*)&vr[l * 64];
    #pragma unroll
    for (int i = 0; i < 8; ++i){
      s16x8 v = src[i];
      *(s16x4*)&vt[l * 68 + i * 8]     = __builtin_shufflevector(v, v, 0, 1, 2, 3);
      *(s16x4*)&vt[l * 68 + i * 8 + 4] = __builtin_shufflevector(v, v, 4, 5, 6, 7);
    }
  }
  f32x4 acc1[4] = {};
  #pragma unroll
  for (int kk = 0; kk < 2; ++kk){
    s16x8 af = *(const s16x8*)&qr[l15 * 64 + kk * 32 + lg * 8];
    #pragma unroll
    for (int dt = 0; dt < 4; ++dt){
      alignas(16) u16 bh[8];
      #pragma unroll
      for (int j = 0; j < 8; ++j)
        bh[j] = vt[(kk * 32 + lg * 8 + j) * 68 + dt * 16 + l15];
      acc1[dt] = mfma16(af, *(const s16x8*)bh, acc1[dt]);
    }
  }
  #pragma unroll
  for (int dt = 0; dt < 4; ++dt)
    #pragma unroll
    for (int j = 0; j < 4; ++j)
      tt[(lg * 4 + j) * 64 + dt * 16 + l15] = f2bf(acc1[dt][j]);
  s16x8 af2[4] = {};
  if (lg < 2){
    #pragma unroll
    for (int m = 0; m < 4; ++m)
      af2[m] = *(const s16x8*)&Qr[(m * 16 + l15) * 16 + lg * 8];
  }
  f32x4 acc2[4][4] = {};
  #pragma unroll
  for (int dt = 0; dt < 4; ++dt){
    alignas(16) u16 bh[8] = {};
    if (lg < 2){
      #pragma unroll
      for (int j = 0; j < 8; ++j)
        bh[j] = tt[(lg * 8 + j) * 64 + dt * 16 + l15];
    }
    s16x8 bf = *(const s16x8*)bh;
    #pragma unroll
    for (int m = 0; m < 4; ++m) acc2[m][dt] = mfma16(af2[m], bf, acc2[m][dt]);
  }
  float* ob = out + ((size_t)b * 512 + c) * 4096;
  #pragma unroll
  for (int m = 0; m < 4; ++m)
    #pragma unroll
    for (int dt = 0; dt < 4; ++dt)
      #pragma unroll
      for (int j = 0; j < 4; ++j)
        ob[(m * 16 + lg * 4 + j) * 64 + dt * 16 + l15] = acc2[m][dt][j];
}

// ---------------------------------------------------------------------------
extern "C" void kernel_launch(void* const* d_in, const int* in_sizes, int n_in,
                              void* d_out, int out_size, void* d_ws, size_t ws_size,
                              hipStream_t stream)
{
  (void)in_sizes; (void)n_in; (void)out_size; (void)ws_size;
  const float* x       = (const float*)d_in[0];
  const float* W_in    = (const float*)d_in[1];
  const float* b_in    = (const float*)d_in[2];
  const float* W_inter = (const float*)d_in[3];
  const float* b_inter = (const float*)d_in[4];
  const float* W_last  = (const float*)d_in[5];
  const float* b_last  = (const float*)d_in[6];
  float* out = (float*)d_out;

  char* ws = (char*)d_ws;
  size_t off = 0;
  auto alloc = [&](size_t bytes) -> u16* {
    u16* p = (u16*)(ws + off);
    off += (bytes + 255) & ~(size_t)255;
    return p;
  };
  u16*  WT_in  = alloc((size_t)1024 * 512 * 2);
  u16*  WTi_rm = alloc((size_t)512 * 512 * 2);
  u16*  WiFL   = alloc((size_t)512 * 512 * 2);
  u16*  WlFL   = alloc((size_t)512 * 512 * 2);
  u16*  WviFL  = alloc((size_t)512 * 512 * 2);
  float* b_vi  = (float*)alloc((size_t)512 * 4);
  u16*  xb     = alloc((size_t)8 * 4096 * 512 * 2);
  u16*  Qp     = alloc((size_t)8 * 512 * 4096 * 2);
  u16*  Kp     = alloc((size_t)8 * 512 * 4096 * 2);
  u16*  T12    = alloc((size_t)8 * 2048 * 512 * 2);
  // aliases (lifetime-checked): Qp,Kp dead after k3 (merged k4 runs after k3)
  u16*  Vpp    = Qp;    // V-plane output of k4V
  u16*  O12    = Kp;    // merged Qk/qK output of k4ab

  k0prep<<<10240, 256, 0, stream>>>(W_in, W_inter, W_last, WT_in, WTi_rm, WiFL, WlFL, x, xb);
  k0b_wvi<<<24, 256, 0, stream>>>(W_in, W_inter, WTi_rm, b_in, b_inter, WviFL, b_vi);
  k1_qk<<<dim3(8, 256), 256, 0, stream>>>(xb, WT_in, b_in, Qp, Kp);
  k3_scores<<<512, 512, 0, stream>>>(Qp, Kp, T12);
  k4_interlast<<<dim3(96, 8), 512, 0, stream>>>(xb, T12, Vpp, O12,
                                                WviFL, b_vi, WiFL, b_inter, WlFL, b_last);
  k56<<<1024, 256, 0, stream>>>(O12, Vpp, out);
}